// Round 3
// baseline (1435.021 us; speedup 1.0000x reference)
//
#include <hip/hip_runtime.h>
#include <math.h>

// BagOfConcepts: inp [8,4096,512] f32, codebook [4096,512] f32
constexpr int D  = 512;
constexpr int K  = 4096;
constexpr int BM = 64;
constexpr int BN = 64;
constexpr int BD_LEG = 32;
constexpr int PAD = 4;

constexpr int   CAP    = 128;        // candidate list per token
#define MARGIN 2.5e-4f               // >= tie window 1.33e-4 (ulp(1024)*2 + 2*err_wc)

typedef short short8v __attribute__((ext_vector_type(8)));
typedef float f32x4   __attribute__((ext_vector_type(4)));

// ws layout (fast path)
constexpr size_t SC_OFF    = 0;           // 4096 f32 = 16384
constexpr size_t IDX_OFF   = 16384;       // 32768 i32 = 131072
constexpr size_t CB_HI_OFF = 147456;      // 4096*512 u16 = 4194304
constexpr size_t CB_LO_OFF = 4341760;     // 4096*512 u16
constexpr size_t WS_NEED   = 8536064;

__device__ inline void f32_split_bf16(float x, unsigned short& h, unsigned short& l) {
    unsigned u  = __float_as_uint(x);
    unsigned hr = u + 0x7FFFu + ((u >> 16) & 1u);      // RNE to bf16
    h = (unsigned short)(hr >> 16);
    float hv = __uint_as_float((unsigned)h << 16);
    float lo = x - hv;                                  // exact
    unsigned v  = __float_as_uint(lo);
    unsigned lr = v + 0x7FFFu + ((v >> 16) & 1u);
    l = (unsigned short)(lr >> 16);
}

// ---------------- sc: s_c[k] = sum_d cb[k][d]^2 (UNCHANGED) ----------------
__global__ __launch_bounds__(256)
void sc_kernel(const float* __restrict__ cb, float* __restrict__ sc) {
    const int row  = blockIdx.x * 4 + (threadIdx.x >> 6);
    const int lane = threadIdx.x & 63;
    const float* r = cb + (size_t)row * D + lane * 8;
    float4 v0 = *(const float4*)r;
    float4 v1 = *(const float4*)(r + 4);
    float s = v0.x * v0.x;
    s += v0.y * v0.y; s += v0.z * v0.z; s += v0.w * v0.w;
    s += v1.x * v1.x; s += v1.y * v1.y; s += v1.z * v1.z; s += v1.w * v1.w;
#pragma unroll
    for (int off = 1; off < 64; off <<= 1) s += __shfl_xor(s, off, 64);
    if (lane == 0) sc[row] = s;
}

// ---------------- split-convert f32 -> bf16 hi/lo planes ----------------
__global__ __launch_bounds__(256)
void cvt_split(const float* __restrict__ src, unsigned short* __restrict__ hi,
               unsigned short* __restrict__ lo) {
    const size_t g = ((size_t)blockIdx.x * 256 + threadIdx.x) * 8;
    float4 v0 = *(const float4*)(src + g);
    float4 v1 = *(const float4*)(src + g + 4);
    float xs[8] = {v0.x, v0.y, v0.z, v0.w, v1.x, v1.y, v1.z, v1.w};
    union { short8v v; unsigned short u[8]; } H, L;
#pragma unroll
    for (int i = 0; i < 8; ++i) f32_split_bf16(xs[i], H.u[i], L.u[i]);
    *(short8v*)(hi + g) = H.v;
    *(short8v*)(lo + g) = L.v;
}

// ---------------- exact sequential dot (bit-identical to legacy order) ----------------
__device__ float exact_dot512(const float* __restrict__ x, const float* __restrict__ c) {
    float s = 0.0f;
#pragma unroll 4
    for (int i = 0; i < 128; ++i) {
        const float4 xv = *(const float4*)(x + i * 4);
        const float4 cv = *(const float4*)(c + i * 4);
        s = fmaf(xv.x, cv.x, s); s = fmaf(xv.y, cv.y, s);
        s = fmaf(xv.z, cv.z, s); s = fmaf(xv.w, cv.w, s);
    }
    return s;
}

// ---------------- MFMA filter + exact rescue (BARRIER-FREE main loop) ----------------
// 256 thr (4 waves), 64 tokens/block. Wave w owns codes {kt*256 + w*64 .. +63} per k-tile.
// A fragments loaded straight from global (L1-shared across the 4 waves): no LDS, no
// per-iter __syncthreads -> no vmcnt(0) drains -> B prefetch stays in flight.
__global__ __launch_bounds__(256, 2)
void vq_mfma(const float* __restrict__ inp, const float* __restrict__ cb,
             const float* __restrict__ sc,
             const unsigned short* __restrict__ a_hi,
             const unsigned short* __restrict__ a_lo,
             const unsigned short* __restrict__ cb_hi,
             const unsigned short* __restrict__ cb_lo,
             int* __restrict__ out_idx) {
    __shared__ float sx[64];
    __shared__ unsigned int cnt[64];
    __shared__ unsigned short list[64 * CAP];           // 16 KB
    __shared__ unsigned long long keys[64];

    const int t    = threadIdx.x;
    const int m0   = blockIdx.x * 64;
    const int lane = t & 63;
    const int w    = t >> 6;
    const int l15  = lane & 15;
    const int lk   = lane >> 4;
    const float FINF = __builtin_huge_valf();

    // ---- s_x prologue: BIT-IDENTICAL to legacy ----
    {
        const int r = t >> 2, p = t & 3;
        const float* row = inp + (size_t)(m0 + r) * D + p * 128;
        float s = 0.0f;
#pragma unroll
        for (int i = 0; i < 32; ++i) {
            float4 v = *(const float4*)(row + i * 4);
            s = fmaf(v.x, v.x, s); s = fmaf(v.y, v.y, s);
            s = fmaf(v.z, v.z, s); s = fmaf(v.w, v.w, s);
        }
        s += __shfl_xor(s, 1, 64);
        s += __shfl_xor(s, 2, 64);
        if (p == 0) sx[r] = s;
    }
    if (t < 64) { cnt[t] = 0u; keys[t] = 0xFFFFFFFFFFFFFFFFull; }
    __syncthreads();   // cnt/keys/sx visible to all waves before use

    // per-lane base pointers (fragment layout: row = l15, k-contig 8 at lk*8)
    const unsigned short* aH = a_hi  + (size_t)(m0 + l15) * D + lk * 8;
    const unsigned short* aL = a_lo  + (size_t)(m0 + l15) * D + lk * 8;
    const unsigned short* bH = cb_hi + (size_t)(w * 64 + l15) * D + lk * 8;
    const unsigned short* bL = cb_lo + (size_t)(w * 64 + l15) * D + lk * 8;

    f32x4 acc[4][4];
    float runmin[4][4];
#pragma unroll
    for (int i = 0; i < 4; ++i)
#pragma unroll
        for (int j = 0; j < 4; ++j) runmin[i][j] = FINF;

    short8v bC[2][4], bN[2][4];

    // preload B for iter 0
#pragma unroll
    for (int nt = 0; nt < 4; ++nt) {
        bC[0][nt] = *(const short8v*)(bH + nt * 8192);
        bC[1][nt] = *(const short8v*)(bL + nt * 8192);
    }

#pragma unroll 2
    for (int iter = 0; iter < 256; ++iter) {
        const int chunk = iter & 15;

        if (chunk == 0) {
#pragma unroll
            for (int i = 0; i < 4; ++i)
#pragma unroll
                for (int j = 0; j < 4; ++j) acc[i][j] = f32x4{0.f, 0.f, 0.f, 0.f};
        }

        // A fragments for THIS iter (global; L1-hot — same lines for all 4 waves)
        short8v af0[4], af1[4];
        {
            const int aoff = chunk * 32;
#pragma unroll
            for (int mt = 0; mt < 4; ++mt) {
                af0[mt] = *(const short8v*)(aH + mt * 8192 + aoff);
                af1[mt] = *(const short8v*)(aL + mt * 8192 + aoff);
            }
        }
        // prefetch B for iter+1 (wrap-index keeps it branchless; last-iter value unused)
        {
            const int i1   = (iter + 1) & 255;
            const int boff = (i1 >> 4) * 131072 + (i1 & 15) * 32;
#pragma unroll
            for (int nt = 0; nt < 4; ++nt) {
                bN[0][nt] = *(const short8v*)(bH + boff + nt * 8192);
                bN[1][nt] = *(const short8v*)(bL + boff + nt * 8192);
            }
        }
        // 48 MFMAs (hh, xh*cl, xl*ch)
#pragma unroll
        for (int mt = 0; mt < 4; ++mt)
#pragma unroll
            for (int nt = 0; nt < 4; ++nt) {
                acc[mt][nt] = __builtin_amdgcn_mfma_f32_16x16x32_bf16(af0[mt], bC[0][nt], acc[mt][nt], 0, 0, 0);
                acc[mt][nt] = __builtin_amdgcn_mfma_f32_16x16x32_bf16(af0[mt], bC[1][nt], acc[mt][nt], 0, 0, 0);
                acc[mt][nt] = __builtin_amdgcn_mfma_f32_16x16x32_bf16(af1[mt], bC[0][nt], acc[mt][nt], 0, 0, 0);
            }

        // k-tile epilogue: running-min + candidate collection (unchanged semantics)
        if (chunk == 15) {
            const int kb        = (iter >> 4) << 8;
            const int code_base = kb + w * 64;
            float scv[4];
#pragma unroll
            for (int nt = 0; nt < 4; ++nt) scv[nt] = sc[code_base + nt * 16 + l15];
#pragma unroll
            for (int mt = 0; mt < 4; ++mt) {
#pragma unroll
                for (int r = 0; r < 4; ++r) {
                    float v0 = fmaf(-2.0f, acc[mt][0][r], scv[0]);
                    float v1 = fmaf(-2.0f, acc[mt][1][r], scv[1]);
                    float v2 = fmaf(-2.0f, acc[mt][2][r], scv[2]);
                    float v3 = fmaf(-2.0f, acc[mt][3][r], scv[3]);
                    float gm = fminf(fminf(v0, v1), fminf(v2, v3));
                    gm = fminf(gm, __shfl_xor(gm, 1, 64));
                    gm = fminf(gm, __shfl_xor(gm, 2, 64));
                    gm = fminf(gm, __shfl_xor(gm, 4, 64));
                    gm = fminf(gm, __shfl_xor(gm, 8, 64));
                    runmin[mt][r] = fminf(runmin[mt][r], gm);
                    const float th = runmin[mt][r] + MARGIN;
                    const int tok = mt * 16 + lk * 4 + r;
                    if (v0 <= th) { unsigned p = atomicAdd(&cnt[tok], 1u); if (p < CAP) list[tok * CAP + p] = (unsigned short)(code_base + l15); }
                    if (v1 <= th) { unsigned p = atomicAdd(&cnt[tok], 1u); if (p < CAP) list[tok * CAP + p] = (unsigned short)(code_base + 16 + l15); }
                    if (v2 <= th) { unsigned p = atomicAdd(&cnt[tok], 1u); if (p < CAP) list[tok * CAP + p] = (unsigned short)(code_base + 32 + l15); }
                    if (v3 <= th) { unsigned p = atomicAdd(&cnt[tok], 1u); if (p < CAP) list[tok * CAP + p] = (unsigned short)(code_base + 48 + l15); }
                }
            }
        }
#pragma unroll
        for (int nt = 0; nt < 4; ++nt) { bC[0][nt] = bN[0][nt]; bC[1][nt] = bN[1][nt]; }
    }

    __syncthreads();   // all waves' cnt/list writes visible before rescue

    // ---- exact rescue: bit-identical scores for candidates; lexicographic (v, idx) min ----
    const float* inp_blk = inp + (size_t)m0 * D;
    for (int slot = t; slot < 64 * CAP; slot += 256) {
        const int tok = slot >> 7;
        const int j   = slot & (CAP - 1);
        unsigned n = cnt[tok]; if (n > CAP) n = CAP;
        if (j < (int)n) {
            const int code = list[slot];
            const float dot = exact_dot512(inp_blk + (size_t)tok * D, cb + (size_t)code * D);
            const float tmp = sx[tok] - 2.0f * dot;      // -2*dot exact => contraction-immune
            const float v   = tmp + sc[code];
            const unsigned long long key =
                ((unsigned long long)__float_as_uint(v) << 32) | (unsigned)code;
            atomicMin(&keys[tok], key);
        }
    }
    // overflow fallback (essentially never taken): full scan for that token
    for (int tok = 0; tok < 64; ++tok) {
        if (cnt[tok] > CAP) {
            for (int code = t; code < K; code += 256) {
                const float dot = exact_dot512(inp_blk + (size_t)tok * D, cb + (size_t)code * D);
                const float tmp = sx[tok] - 2.0f * dot;
                const float v   = tmp + sc[code];
                const unsigned long long key =
                    ((unsigned long long)__float_as_uint(v) << 32) | (unsigned)code;
                atomicMin(&keys[tok], key);
            }
        }
    }
    __syncthreads();
    if (t < 64) out_idx[m0 + t] = (int)(keys[t] & 0xFFFFFFFFull);
}

// ---------------- gather: bit-exact codebook row copy ----------------
__global__ __launch_bounds__(256)
void gather_kernel(const float* __restrict__ cb, const int* __restrict__ idx,
                   float* __restrict__ out) {
    const int m0 = blockIdx.x * 64;
    __shared__ int bidx[64];
    if (threadIdx.x < 64) bidx[threadIdx.x] = idx[m0 + threadIdx.x];
    __syncthreads();
    for (int q = threadIdx.x; q < 64 * (D / 4); q += 256) {
        const int r = q >> 7;
        const int c = (q & 127) * 4;
        *(float4*)(out + (size_t)(m0 + r) * D + c) = *(const float4*)(cb + (size_t)bidx[r] * D + c);
    }
}

// ================= LEGACY (round-1 passing kernel, fallback if ws too small) ==========
__global__ __launch_bounds__(256)
void vq_kernel(const float* __restrict__ inp, const float* __restrict__ cb,
               const float* __restrict__ sc, float* __restrict__ out) {
    __shared__ __align__(16) float As[BD_LEG][BM + PAD];
    __shared__ __align__(16) float Bs[BD_LEG][BN + PAD];
    __shared__ float sxl[BM];
    __shared__ float scs[BN];
    __shared__ int   bidx[BM];

    const int t  = threadIdx.x;
    const int m0 = blockIdx.x * BM;
    const int tm = t >> 4;
    const int tn = t & 15;
    const float FINF = __builtin_huge_valf();

    {
        const int r = t >> 2, p = t & 3;
        const float* row = inp + (size_t)(m0 + r) * D + p * 128;
        float s = 0.0f;
#pragma unroll
        for (int i = 0; i < 32; ++i) {
            float4 v = *(const float4*)(row + i * 4);
            s = fmaf(v.x, v.x, s); s = fmaf(v.y, v.y, s);
            s = fmaf(v.z, v.z, s); s = fmaf(v.w, v.w, s);
        }
        s += __shfl_xor(s, 1, 64);
        s += __shfl_xor(s, 2, 64);
        if (p == 0) sxl[r] = s;
    }
    __syncthreads();

    float sxm[4];
#pragma unroll
    for (int i = 0; i < 4; ++i) sxm[i] = sxl[tm * 4 + i];

    float runv[4] = {FINF, FINF, FINF, FINF};
    int   runi[4] = {0, 0, 0, 0};
    const int dq = (t & 7) << 2;
    const int mr = t >> 3;

#pragma unroll 1
    for (int kb = 0; kb < K; kb += BN) {
        __syncthreads();
        if (t < BN) scs[t] = sc[kb + t];

        float accl[4][4];
#pragma unroll
        for (int i = 0; i < 4; ++i)
#pragma unroll
            for (int j = 0; j < 4; ++j) accl[i][j] = 0.0f;

#pragma unroll 1
        for (int db = 0; db < D; db += BD_LEG) {
            const float* ap = inp + (size_t)(m0 + mr) * D + db + dq;
            const float* bp = cb  + (size_t)(kb + mr) * D + db + dq;
            float4 av0 = *(const float4*)ap;
            float4 av1 = *(const float4*)(ap + (size_t)32 * D);
            float4 bv0 = *(const float4*)bp;
            float4 bv1 = *(const float4*)(bp + (size_t)32 * D);
            __syncthreads();
            As[dq + 0][mr] = av0.x; As[dq + 1][mr] = av0.y;
            As[dq + 2][mr] = av0.z; As[dq + 3][mr] = av0.w;
            As[dq + 0][mr + 32] = av1.x; As[dq + 1][mr + 32] = av1.y;
            As[dq + 2][mr + 32] = av1.z; As[dq + 3][mr + 32] = av1.w;
            Bs[dq + 0][mr] = bv0.x; Bs[dq + 1][mr] = bv0.y;
            Bs[dq + 2][mr] = bv0.z; Bs[dq + 3][mr] = bv0.w;
            Bs[dq + 0][mr + 32] = bv1.x; Bs[dq + 1][mr + 32] = bv1.y;
            Bs[dq + 2][mr + 32] = bv1.z; Bs[dq + 3][mr + 32] = bv1.w;
            __syncthreads();
#pragma unroll
            for (int d = 0; d < BD_LEG; ++d) {
                const float4 a = *(const float4*)(&As[d][tm * 4]);
                const float4 b = *(const float4*)(&Bs[d][tn * 4]);
                float af[4] = {a.x, a.y, a.z, a.w};
                float bf[4] = {b.x, b.y, b.z, b.w};
#pragma unroll
                for (int i = 0; i < 4; ++i)
#pragma unroll
                    for (int j = 0; j < 4; ++j)
                        accl[i][j] = fmaf(af[i], bf[j], accl[i][j]);
            }
        }
#pragma unroll
        for (int i = 0; i < 4; ++i) {
            float bv = FINF;
            int   bi = 0x7fffffff;
#pragma unroll
            for (int j = 0; j < 4; ++j) {
                const float p = accl[i][j];
                const float tmp = sxm[i] - 2.0f * p;
                const float v   = tmp + scs[tn * 4 + j];
                const int  idx  = kb + tn * 4 + j;
                if (v < bv) { bv = v; bi = idx; }
            }
#pragma unroll
            for (int off = 1; off < 16; off <<= 1) {
                const float ov = __shfl_xor(bv, off, 64);
                const int   oi = __shfl_xor(bi, off, 64);
                if (ov < bv || (ov == bv && oi < bi)) { bv = ov; bi = oi; }
            }
            if (bv < runv[i]) { runv[i] = bv; runi[i] = bi; }
        }
    }
    if (tn == 0) {
#pragma unroll
        for (int i = 0; i < 4; ++i) bidx[tm * 4 + i] = runi[i];
    }
    __syncthreads();
#pragma unroll 1
    for (int q = t; q < BM * (D / 4); q += 256) {
        const int r = q >> 7;
        const int c = (q & 127) * 4;
        const float4 v = *(const float4*)(cb + (size_t)bidx[r] * D + c);
        *(float4*)(out + (size_t)(m0 + r) * D + c) = v;
    }
}

extern "C" void kernel_launch(void* const* d_in, const int* in_sizes, int n_in,
                              void* d_out, int out_size, void* d_ws, size_t ws_size,
                              hipStream_t stream) {
    const float* inp = (const float*)d_in[0];
    const float* cb  = (const float*)d_in[1];
    float* out = (float*)d_out;
    float* sc  = (float*)d_ws;
    const int tokens = in_sizes[0] / D;     // 32768

    if (ws_size >= WS_NEED && (tokens % 64) == 0 &&
        (size_t)out_size * sizeof(float) >= (size_t)tokens * D * 4) {
        int* idx = (int*)((char*)d_ws + IDX_OFF);
        unsigned short* cbh = (unsigned short*)((char*)d_ws + CB_HI_OFF);
        unsigned short* cbl = (unsigned short*)((char*)d_ws + CB_LO_OFF);
        unsigned short* ah  = (unsigned short*)d_out;               // d_out as scratch
        unsigned short* al  = ah + (size_t)tokens * D;

        sc_kernel<<<K / 4, 256, 0, stream>>>(cb, sc);
        cvt_split<<<(K * D) / 2048, 256, 0, stream>>>(cb, cbh, cbl);
        cvt_split<<<(tokens * D) / 2048, 256, 0, stream>>>(inp, ah, al);
        vq_mfma<<<tokens / 64, 256, 0, stream>>>(inp, cb, sc, ah, al, cbh, cbl, idx);
        gather_kernel<<<tokens / 64, 256, 0, stream>>>(cb, idx, out);
    } else {
        sc_kernel<<<K / 4, 256, 0, stream>>>(cb, sc);
        vq_kernel<<<tokens / BM, 256, 0, stream>>>(inp, cb, sc, out);
    }
}

// Round 4
// 944.918 us; speedup vs baseline: 1.5187x; 1.5187x over previous
//
#include <hip/hip_runtime.h>
#include <math.h>

// BagOfConcepts: inp [8,4096,512] f32, codebook [4096,512] f32
constexpr int D  = 512;
constexpr int K  = 4096;
constexpr int BM = 64;
constexpr int BN = 64;
constexpr int BD_LEG = 32;
constexpr int PAD = 4;

constexpr int CAP = 64;              // candidate list per token
#define MARGIN 2.0e-3f               // >= W + 2E = 1.33e-4 + 2*7e-4 = 1.52e-3 (worst-case bound)

typedef short short8v __attribute__((ext_vector_type(8)));
typedef float f32x4   __attribute__((ext_vector_type(4)));

// ws layout (fast path)
constexpr size_t SC_OFF    = 0;           // 4096 f32 = 16384
constexpr size_t IDX_OFF   = 16384;       // 32768 i32 = 131072
constexpr size_t CB_HI_OFF = 147456;      // 4096*512 u16 = 4194304
constexpr size_t WS_NEED   = CB_HI_OFF + (size_t)K * D * 2;   // ~4.34 MB

__device__ inline unsigned short rne_bf16(float x) {
    unsigned u = __float_as_uint(x);
    return (unsigned short)((u + 0x7FFFu + ((u >> 16) & 1u)) >> 16);
}

// ---------------- sc: s_c[k] = sum_d cb[k][d]^2 (UNCHANGED, validated) ----------------
__global__ __launch_bounds__(256)
void sc_kernel(const float* __restrict__ cb, float* __restrict__ sc) {
    const int row  = blockIdx.x * 4 + (threadIdx.x >> 6);
    const int lane = threadIdx.x & 63;
    const float* r = cb + (size_t)row * D + lane * 8;
    float4 v0 = *(const float4*)r;
    float4 v1 = *(const float4*)(r + 4);
    float s = v0.x * v0.x;
    s += v0.y * v0.y; s += v0.z * v0.z; s += v0.w * v0.w;
    s += v1.x * v1.x; s += v1.y * v1.y; s += v1.z * v1.z; s += v1.w * v1.w;
#pragma unroll
    for (int off = 1; off < 64; off <<= 1) s += __shfl_xor(s, off, 64);
    if (lane == 0) sc[row] = s;
}

// ---------------- f32 -> bf16 (hi plane only, codebook) ----------------
__global__ __launch_bounds__(256)
void cvt_hi(const float* __restrict__ src, unsigned short* __restrict__ hi) {
    const size_t g = ((size_t)blockIdx.x * 256 + threadIdx.x) * 8;
    float4 v0 = *(const float4*)(src + g);
    float4 v1 = *(const float4*)(src + g + 4);
    float xs[8] = {v0.x, v0.y, v0.z, v0.w, v1.x, v1.y, v1.z, v1.w};
    union { short8v v; unsigned short u[8]; } H;
#pragma unroll
    for (int i = 0; i < 8; ++i) H.u[i] = rne_bf16(xs[i]);
    *(short8v*)(hi + g) = H.v;
}

// ---------------- exact sequential dot (bit-identical to validated path) ----------------
__device__ float exact_dot512(const float* __restrict__ x, const float* __restrict__ c) {
    float s = 0.0f;
#pragma unroll 4
    for (int i = 0; i < 128; ++i) {
        const float4 xv = *(const float4*)(x + i * 4);
        const float4 cv = *(const float4*)(c + i * 4);
        s = fmaf(xv.x, cv.x, s); s = fmaf(xv.y, cv.y, s);
        s = fmaf(xv.z, cv.z, s); s = fmaf(xv.w, cv.w, s);
    }
    return s;
}

// ---------------- MFMA filter (A resident in LDS, barrier-free loop) + exact rescue ----
// 256 thr (4 waves), 64 tokens/block. Wave w owns codes {kt*256 + w*64 .. +63}.
// A staged ONCE into LDS (bf16, layout halfidx=(d8*64+row)*8: ds_read_b128 frags are
// 16 consecutive 16B lines -> minimal LDS passes). Main loop: 4 global B loads
// (depth-2 prefetch, 4-buffer ring, static indices via full unroll), 4 ds_read_b128
// (double-buffered), 16 MFMAs. NO __syncthreads in the loop.
__global__ __launch_bounds__(256, 2)
void vq_mfma(const float* __restrict__ inp, const float* __restrict__ cb,
             const float* __restrict__ sc,
             const unsigned short* __restrict__ cb_hi,
             int* __restrict__ out_idx) {
    __shared__ __align__(16) unsigned short A_lds[64 * 512];   // 64 KB
    __shared__ float sx[64];
    __shared__ unsigned int cnt[64];
    __shared__ unsigned short list[64 * CAP];                  // 8 KB
    __shared__ unsigned long long keys[64];

    const int t    = threadIdx.x;
    const int m0   = blockIdx.x * 64;
    const int lane = t & 63;
    const int w    = t >> 6;
    const int l15  = lane & 15;
    const int lk   = lane >> 4;
    const float FINF = __builtin_huge_valf();

    // ---- s_x prologue: BIT-IDENTICAL to validated rounds ----
    {
        const int r = t >> 2, p = t & 3;
        const float* row = inp + (size_t)(m0 + r) * D + p * 128;
        float s = 0.0f;
#pragma unroll
        for (int i = 0; i < 32; ++i) {
            float4 v = *(const float4*)(row + i * 4);
            s = fmaf(v.x, v.x, s); s = fmaf(v.y, v.y, s);
            s = fmaf(v.z, v.z, s); s = fmaf(v.w, v.w, s);
        }
        s += __shfl_xor(s, 1, 64);
        s += __shfl_xor(s, 2, 64);
        if (p == 0) sx[r] = s;
    }
    if (t < 64) { cnt[t] = 0u; keys[t] = 0xFFFFFFFFFFFFFFFFull; }

    // ---- stage A: f32 inp -> bf16 LDS, layout (d8*64 + row)*8 halves ----
    {
        const int row  = t & 63;
        const int dsub = t >> 6;
#pragma unroll
        for (int p = 0; p < 16; ++p) {
            const int d8 = p * 4 + dsub;                 // 0..63
            const float* s = inp + (size_t)(m0 + row) * D + d8 * 8;
            float4 va = *(const float4*)s;
            float4 vb = *(const float4*)(s + 4);
            float xs[8] = {va.x, va.y, va.z, va.w, vb.x, vb.y, vb.z, vb.w};
            union { short8v v; unsigned short u[8]; } H;
#pragma unroll
            for (int i = 0; i < 8; ++i) H.u[i] = rne_bf16(xs[i]);
            *(short8v*)(&A_lds[(((d8 << 6) + row)) << 3]) = H.v;
        }
    }
    __syncthreads();   // A_lds + cnt/keys/sx visible; ONLY barrier before rescue

    // per-lane B base: code row (w*64 + nt*16 + l15), halves offset lk*8
    const unsigned short* bBase = cb_hi + (size_t)(w * 64 + l15) * D + lk * 8;

    f32x4 acc[4][4];
    float runmin[4][4];
#pragma unroll
    for (int i = 0; i < 4; ++i)
#pragma unroll
        for (int j = 0; j < 4; ++j) runmin[i][j] = FINF;

    short8v B[4][4];    // 4-slot ring, prefetch distance 2 (static idx via full unroll)
    short8v A2[2][4];   // A-fragment double buffer

    // prologue: prefetch flat iters 0,1; preload A chunk 0
#pragma unroll
    for (int nt = 0; nt < 4; ++nt) {
        B[0][nt] = *(const short8v*)(bBase + (size_t)nt * (16 * D));
        B[1][nt] = *(const short8v*)(bBase + (size_t)nt * (16 * D) + 32);
    }
#pragma unroll
    for (int mt = 0; mt < 4; ++mt)
        A2[0][mt] = *(const short8v*)(&A_lds[(((lk << 6) + mt * 16 + l15)) << 3]);

    for (int kt = 0; kt < 16; ++kt) {
#pragma unroll
        for (int c = 0; c < 16; ++c) {
            if (c == 0) {
#pragma unroll
                for (int i = 0; i < 4; ++i)
#pragma unroll
                    for (int j = 0; j < 4; ++j) acc[i][j] = f32x4{0.f, 0.f, 0.f, 0.f};
            }
            // B prefetch for flat iter +2 (wrap keeps it branchless; wrapped loads unused)
            {
                const int f2 = ((kt << 4) + c + 2) & 255;
                const size_t off = (size_t)(f2 >> 4) * (256 * D) + (size_t)(f2 & 15) * 32;
#pragma unroll
                for (int nt = 0; nt < 4; ++nt)
                    B[(c + 2) & 3][nt] = *(const short8v*)(bBase + (size_t)nt * (16 * D) + off);
            }
            // A-fragment prefetch for chunk (c+1)&15 (chunk 0 identical across kt)
            {
                const int c1 = (c + 1) & 15;
#pragma unroll
                for (int mt = 0; mt < 4; ++mt)
                    A2[(c + 1) & 1][mt] =
                        *(const short8v*)(&A_lds[((((c1 * 4 + lk) << 6) + mt * 16 + l15)) << 3]);
            }
            // 16 MFMAs (hi-only)
#pragma unroll
            for (int mt = 0; mt < 4; ++mt)
#pragma unroll
                for (int nt = 0; nt < 4; ++nt)
                    acc[mt][nt] = __builtin_amdgcn_mfma_f32_16x16x32_bf16(
                        A2[c & 1][mt], B[c & 3][nt], acc[mt][nt], 0, 0, 0);

            // k-tile epilogue: running-min + candidate collection (validated semantics)
            if (c == 15) {
                const int code_base = (kt << 8) + w * 64;
                float scv[4];
#pragma unroll
                for (int nt = 0; nt < 4; ++nt) scv[nt] = sc[code_base + nt * 16 + l15];
#pragma unroll
                for (int mt = 0; mt < 4; ++mt) {
#pragma unroll
                    for (int r = 0; r < 4; ++r) {
                        float v0 = fmaf(-2.0f, acc[mt][0][r], scv[0]);
                        float v1 = fmaf(-2.0f, acc[mt][1][r], scv[1]);
                        float v2 = fmaf(-2.0f, acc[mt][2][r], scv[2]);
                        float v3 = fmaf(-2.0f, acc[mt][3][r], scv[3]);
                        float gm = fminf(fminf(v0, v1), fminf(v2, v3));
                        gm = fminf(gm, __shfl_xor(gm, 1, 64));
                        gm = fminf(gm, __shfl_xor(gm, 2, 64));
                        gm = fminf(gm, __shfl_xor(gm, 4, 64));
                        gm = fminf(gm, __shfl_xor(gm, 8, 64));
                        runmin[mt][r] = fminf(runmin[mt][r], gm);
                        const float th = runmin[mt][r] + MARGIN;
                        const int tok = mt * 16 + lk * 4 + r;
                        if (v0 <= th) { unsigned p = atomicAdd(&cnt[tok], 1u); if (p < CAP) list[tok * CAP + p] = (unsigned short)(code_base + l15); }
                        if (v1 <= th) { unsigned p = atomicAdd(&cnt[tok], 1u); if (p < CAP) list[tok * CAP + p] = (unsigned short)(code_base + 16 + l15); }
                        if (v2 <= th) { unsigned p = atomicAdd(&cnt[tok], 1u); if (p < CAP) list[tok * CAP + p] = (unsigned short)(code_base + 32 + l15); }
                        if (v3 <= th) { unsigned p = atomicAdd(&cnt[tok], 1u); if (p < CAP) list[tok * CAP + p] = (unsigned short)(code_base + 48 + l15); }
                    }
                }
            }
        }
    }

    __syncthreads();   // all waves' cnt/list writes visible before rescue

    // ---- exact rescue: bit-identical scores; lexicographic (v, idx) min ----
    const float* inp_blk = inp + (size_t)m0 * D;
    for (int slot = t; slot < 64 * CAP; slot += 256) {
        const int tok = slot / CAP;
        const int j   = slot & (CAP - 1);
        unsigned n = cnt[tok]; if (n > CAP) n = CAP;
        if (j < (int)n) {
            const int code = list[slot];
            const float dot = exact_dot512(inp_blk + (size_t)tok * D, cb + (size_t)code * D);
            const float tmp = sx[tok] - 2.0f * dot;   // -2*dot exact => contraction-immune
            const float v   = tmp + sc[code];
            const unsigned long long key =
                ((unsigned long long)__float_as_uint(v) << 32) | (unsigned)code;
            atomicMin(&keys[tok], key);
        }
    }
    // overflow fallback (essentially never taken): full scan for that token
    for (int tok = 0; tok < 64; ++tok) {
        if (cnt[tok] > CAP) {
            for (int code = t; code < K; code += 256) {
                const float dot = exact_dot512(inp_blk + (size_t)tok * D, cb + (size_t)code * D);
                const float tmp = sx[tok] - 2.0f * dot;
                const float v   = tmp + sc[code];
                const unsigned long long key =
                    ((unsigned long long)__float_as_uint(v) << 32) | (unsigned)code;
                atomicMin(&keys[tok], key);
            }
        }
    }
    __syncthreads();
    if (t < 64) out_idx[m0 + t] = (int)(keys[t] & 0xFFFFFFFFull);
}

// ---------------- gather: bit-exact codebook row copy ----------------
__global__ __launch_bounds__(256)
void gather_kernel(const float* __restrict__ cb, const int* __restrict__ idx,
                   float* __restrict__ out) {
    const int m0 = blockIdx.x * 64;
    __shared__ int bidx[64];
    if (threadIdx.x < 64) bidx[threadIdx.x] = idx[m0 + threadIdx.x];
    __syncthreads();
    for (int q = threadIdx.x; q < 64 * (D / 4); q += 256) {
        const int r = q >> 7;
        const int c = (q & 127) * 4;
        *(float4*)(out + (size_t)(m0 + r) * D + c) = *(const float4*)(cb + (size_t)bidx[r] * D + c);
    }
}

// ================= LEGACY (round-1 passing kernel, fallback if ws too small) ==========
__global__ __launch_bounds__(256)
void vq_kernel(const float* __restrict__ inp, const float* __restrict__ cb,
               const float* __restrict__ sc, float* __restrict__ out) {
    __shared__ __align__(16) float As[BD_LEG][BM + PAD];
    __shared__ __align__(16) float Bs[BD_LEG][BN + PAD];
    __shared__ float sxl[BM];
    __shared__ float scs[BN];
    __shared__ int   bidx[BM];

    const int t  = threadIdx.x;
    const int m0 = blockIdx.x * BM;
    const int tm = t >> 4;
    const int tn = t & 15;
    const float FINF = __builtin_huge_valf();

    {
        const int r = t >> 2, p = t & 3;
        const float* row = inp + (size_t)(m0 + r) * D + p * 128;
        float s = 0.0f;
#pragma unroll
        for (int i = 0; i < 32; ++i) {
            float4 v = *(const float4*)(row + i * 4);
            s = fmaf(v.x, v.x, s); s = fmaf(v.y, v.y, s);
            s = fmaf(v.z, v.z, s); s = fmaf(v.w, v.w, s);
        }
        s += __shfl_xor(s, 1, 64);
        s += __shfl_xor(s, 2, 64);
        if (p == 0) sxl[r] = s;
    }
    __syncthreads();

    float sxm[4];
#pragma unroll
    for (int i = 0; i < 4; ++i) sxm[i] = sxl[tm * 4 + i];

    float runv[4] = {FINF, FINF, FINF, FINF};
    int   runi[4] = {0, 0, 0, 0};
    const int dq = (t & 7) << 2;
    const int mr = t >> 3;

#pragma unroll 1
    for (int kb = 0; kb < K; kb += BN) {
        __syncthreads();
        if (t < BN) scs[t] = sc[kb + t];

        float accl[4][4];
#pragma unroll
        for (int i = 0; i < 4; ++i)
#pragma unroll
            for (int j = 0; j < 4; ++j) accl[i][j] = 0.0f;

#pragma unroll 1
        for (int db = 0; db < D; db += BD_LEG) {
            const float* ap = inp + (size_t)(m0 + mr) * D + db + dq;
            const float* bp = cb  + (size_t)(kb + mr) * D + db + dq;
            float4 av0 = *(const float4*)ap;
            float4 av1 = *(const float4*)(ap + (size_t)32 * D);
            float4 bv0 = *(const float4*)bp;
            float4 bv1 = *(const float4*)(bp + (size_t)32 * D);
            __syncthreads();
            As[dq + 0][mr] = av0.x; As[dq + 1][mr] = av0.y;
            As[dq + 2][mr] = av0.z; As[dq + 3][mr] = av0.w;
            As[dq + 0][mr + 32] = av1.x; As[dq + 1][mr + 32] = av1.y;
            As[dq + 2][mr + 32] = av1.z; As[dq + 3][mr + 32] = av1.w;
            Bs[dq + 0][mr] = bv0.x; Bs[dq + 1][mr] = bv0.y;
            Bs[dq + 2][mr] = bv0.z; Bs[dq + 3][mr] = bv0.w;
            Bs[dq + 0][mr + 32] = bv1.x; Bs[dq + 1][mr + 32] = bv1.y;
            Bs[dq + 2][mr + 32] = bv1.z; Bs[dq + 3][mr + 32] = bv1.w;
            __syncthreads();
#pragma unroll
            for (int d = 0; d < BD_LEG; ++d) {
                const float4 a = *(const float4*)(&As[d][tm * 4]);
                const float4 b = *(const float4*)(&Bs[d][tn * 4]);
                float af[4] = {a.x, a.y, a.z, a.w};
                float bf[4] = {b.x, b.y, b.z, b.w};
#pragma unroll
                for (int i = 0; i < 4; ++i)
#pragma unroll
                    for (int j = 0; j < 4; ++j)
                        accl[i][j] = fmaf(af[i], bf[j], accl[i][j]);
            }
        }
#pragma unroll
        for (int i = 0; i < 4; ++i) {
            float bv = FINF;
            int   bi = 0x7fffffff;
#pragma unroll
            for (int j = 0; j < 4; ++j) {
                const float p = accl[i][j];
                const float tmp = sxm[i] - 2.0f * p;
                const float v   = tmp + scs[tn * 4 + j];
                const int  idx  = kb + tn * 4 + j;
                if (v < bv) { bv = v; bi = idx; }
            }
#pragma unroll
            for (int off = 1; off < 16; off <<= 1) {
                const float ov = __shfl_xor(bv, off, 64);
                const int   oi = __shfl_xor(bi, off, 64);
                if (ov < bv || (ov == bv && oi < bi)) { bv = ov; bi = oi; }
            }
            if (bv < runv[i]) { runv[i] = bv; runi[i] = bi; }
        }
    }
    if (tn == 0) {
#pragma unroll
        for (int i = 0; i < 4; ++i) bidx[tm * 4 + i] = runi[i];
    }
    __syncthreads();
#pragma unroll 1
    for (int q = t; q < BM * (D / 4); q += 256) {
        const int r = q >> 7;
        const int c = (q & 127) * 4;
        const float4 v = *(const float4*)(cb + (size_t)bidx[r] * D + c);
        *(float4*)(out + (size_t)(m0 + r) * D + c) = v;
    }
}

extern "C" void kernel_launch(void* const* d_in, const int* in_sizes, int n_in,
                              void* d_out, int out_size, void* d_ws, size_t ws_size,
                              hipStream_t stream) {
    const float* inp = (const float*)d_in[0];
    const float* cb  = (const float*)d_in[1];
    float* out = (float*)d_out;
    float* sc  = (float*)d_ws;
    const int tokens = in_sizes[0] / D;     // 32768

    if (ws_size >= WS_NEED && (tokens % 64) == 0) {
        int* idx = (int*)((char*)d_ws + IDX_OFF);
        unsigned short* cbh = (unsigned short*)((char*)d_ws + CB_HI_OFF);

        sc_kernel<<<K / 4, 256, 0, stream>>>(cb, sc);
        cvt_hi<<<(K * D) / 2048, 256, 0, stream>>>(cb, cbh);
        vq_mfma<<<tokens / 64, 256, 0, stream>>>(inp, cb, sc, cbh, idx);
        gather_kernel<<<tokens / 64, 256, 0, stream>>>(cb, idx, out);
    } else {
        sc_kernel<<<K / 4, 256, 0, stream>>>(cb, sc);
        vq_kernel<<<tokens / BM, 256, 0, stream>>>(inp, cb, sc, out);
    }
}

// Round 6
// 627.660 us; speedup vs baseline: 2.2863x; 1.5055x over previous
//
#include <hip/hip_runtime.h>
#include <math.h>

// BagOfConcepts: inp [8,4096,512] f32, codebook [4096,512] f32
constexpr int D  = 512;
constexpr int K  = 4096;
constexpr int BM = 64;
constexpr int BN = 64;
constexpr int BD_LEG = 32;
constexpr int PAD = 4;

#define MARGIN 2.5e-3f     // >= 2*E_score (~1.4e-3 high-prob bound); superset-safe to raise
constexpr int RCAP = 12;   // codes per (token,tile) record

typedef short short8v __attribute__((ext_vector_type(8)));
typedef float f32x4   __attribute__((ext_vector_type(4)));

// ws layout (fast path)
constexpr size_t SC_OFF   = 0;                         // 4096 f32
constexpr size_t SX_OFF   = 16384;                     // 32768 f32
constexpr size_t IDX_OFF  = SX_OFF + 131072;           // 32768 i32
constexpr size_t CBP_OFF  = IDX_OFF + 131072;          // 4096*512 u16 perm
constexpr size_t WS_NEED  = CBP_OFF + (size_t)K * D * 2;   // ~4.47 MB

__device__ inline unsigned short rne_bf16(float x) {
    unsigned u = __float_as_uint(x);
    return (unsigned short)((u + 0x7FFFu + ((u >> 16) & 1u)) >> 16);
}
__device__ inline unsigned ordkey(float f) {            // monotone f32 -> u32
    unsigned u = __float_as_uint(f);
    return (u & 0x80000000u) ? ~u : (u | 0x80000000u);
}
__device__ inline float fromkey(unsigned k) {
    unsigned u = (k & 0x80000000u) ? (k ^ 0x80000000u) : ~k;
    return __uint_as_float(u);
}
__device__ inline void gload16(const void* g, void* l) {
    __builtin_amdgcn_global_load_lds(
        (const __attribute__((address_space(1))) unsigned*)g,
        (__attribute__((address_space(3))) unsigned*)l, 16, 0, 0);
}

// ---------------- sc: s_c[k] = sum_d cb[k][d]^2 (UNCHANGED, validated) ----------------
__global__ __launch_bounds__(256)
void sc_kernel(const float* __restrict__ cb, float* __restrict__ sc) {
    const int row  = blockIdx.x * 4 + (threadIdx.x >> 6);
    const int lane = threadIdx.x & 63;
    const float* r = cb + (size_t)row * D + lane * 8;
    float4 v0 = *(const float4*)r;
    float4 v1 = *(const float4*)(r + 4);
    float s = v0.x * v0.x;
    s += v0.y * v0.y; s += v0.z * v0.z; s += v0.w * v0.w;
    s += v1.x * v1.x; s += v1.y * v1.y; s += v1.z * v1.z; s += v1.w * v1.w;
#pragma unroll
    for (int off = 1; off < 64; off <<= 1) s += __shfl_xor(s, off, 64);
    if (lane == 0) sc[row] = s;
}

// ---------------- sx: BIT-IDENTICAL arithmetic to validated prologue ----------------
__global__ __launch_bounds__(256)
void sx_kernel(const float* __restrict__ inp, float* __restrict__ sxg) {
    const int t = threadIdx.x;
    const int m0 = blockIdx.x * 64;
    const int r = t >> 2, p = t & 3;
    const float* row = inp + (size_t)(m0 + r) * D + p * 128;
    float s = 0.0f;
#pragma unroll
    for (int i = 0; i < 32; ++i) {
        float4 v = *(const float4*)(row + i * 4);
        s = fmaf(v.x, v.x, s); s = fmaf(v.y, v.y, s);
        s = fmaf(v.z, v.z, s); s = fmaf(v.w, v.w, s);
    }
    s += __shfl_xor(s, 1, 64);
    s += __shfl_xor(s, 2, 64);
    if (p == 0) sxg[m0 + r] = s;
}

// ------------- permute+convert f32 -> bf16 in LDS-image order -------------
// slot8 s = [tile][db(16)][j(4)][row(128)]; content = src[tile*128+row][db*32+j*8 ..+8]
__global__ __launch_bounds__(256)
void cvt_perm(const float* __restrict__ src, unsigned short* __restrict__ dst) {
    const int s   = blockIdx.x * 256 + threadIdx.x;
    const int tile = s >> 13;
    const int db  = (s >> 9) & 15;
    const int j   = (s >> 7) & 3;
    const int row = s & 127;
    const float* sp = src + (size_t)(tile * 128 + row) * D + db * 32 + j * 8;
    float4 v0 = *(const float4*)sp;
    float4 v1 = *(const float4*)(sp + 4);
    float xs[8] = {v0.x, v0.y, v0.z, v0.w, v1.x, v1.y, v1.z, v1.w};
    union { short8v v; unsigned short u[8]; } H;
#pragma unroll
    for (int i = 0; i < 8; ++i) H.u[i] = rne_bf16(xs[i]);
    *(short8v*)(dst + (size_t)s * 8) = H.v;
}

// ---------------- exact sequential dot (bit-identical to validated path) ----------------
__device__ float exact_dot512(const float* __restrict__ x, const float* __restrict__ c) {
    float s = 0.0f;
#pragma unroll 4
    for (int i = 0; i < 128; ++i) {
        const float4 xv = *(const float4*)(x + i * 4);
        const float4 cv = *(const float4*)(c + i * 4);
        s = fmaf(xv.x, cv.x, s); s = fmaf(xv.y, cv.y, s);
        s = fmaf(xv.z, cv.z, s); s = fmaf(xv.w, cv.w, s);
    }
    return s;
}

// ---------------- stage 1: m97-style 128x128 tile GEMM + per-tile argmin records ------
// Units: lds[] indices are HALVES. One buffer = 8192 halves (A at +0, B at +4096).
// One d-chunk = 512 slot8 = 4096 halves. Staging slot s = q*256+t in [0,512).
__global__ __launch_bounds__(256)
void score_kernel(const unsigned short* __restrict__ a_perm,
                  const unsigned short* __restrict__ b_perm,
                  const float* __restrict__ sc,
                  char* __restrict__ records) {
    __shared__ __align__(16) unsigned short lds[16384];   // 32 KB: [buf:2][8192 halves]
    __shared__ unsigned minsh[128];
    __shared__ unsigned cntsh[128];
    __shared__ unsigned short listsh[128][RCAP];

    const int t    = threadIdx.x;
    const int lane = t & 63;
    const int w    = t >> 6;
    const int wm   = w >> 1, wn = w & 1;
    const int l15  = lane & 15;
    const int lk   = lane >> 4;
    const int bm   = blockIdx.x >> 5;
    const int bn   = blockIdx.x & 31;

    const unsigned short* aseg = a_perm + (size_t)bm * (16 * 4096);  // 65536 halves/tile
    const unsigned short* bseg = b_perm + (size_t)bn * (16 * 4096);

    if (t < 128) { minsh[t] = 0xFFFFFFFFu; cntsh[t] = 0u; }

    // stage db=0 into buf0: source slot8 = 0*512 + s; dest halves = s*8 (A) / 4096+s*8 (B)
    gload16(aseg + (size_t)(0 * 512 + 0 * 256 + t) * 8, &lds[(0 * 256 + w * 64) * 8]);
    gload16(aseg + (size_t)(0 * 512 + 1 * 256 + t) * 8, &lds[(1 * 256 + w * 64) * 8]);
    gload16(bseg + (size_t)(0 * 512 + 0 * 256 + t) * 8, &lds[4096 + (0 * 256 + w * 64) * 8]);
    gload16(bseg + (size_t)(0 * 512 + 1 * 256 + t) * 8, &lds[4096 + (1 * 256 + w * 64) * 8]);
    __syncthreads();

    f32x4 acc[4][4];
#pragma unroll
    for (int i = 0; i < 4; ++i)
#pragma unroll
        for (int j = 0; j < 4; ++j) acc[i][j] = f32x4{0.f, 0.f, 0.f, 0.f};

#pragma unroll 1
    for (int db = 0; db < 16; ++db) {
        const int cur = (db & 1) * 8192;          // halves offset of current buf
        const int nxt = 8192 - cur;
        const int dn  = (db + 1) & 15;            // db=15 re-stages chunk0 into idle buf (harmless)

        gload16(aseg + (size_t)(dn * 512 + 0 * 256 + t) * 8, &lds[nxt + (0 * 256 + w * 64) * 8]);
        gload16(aseg + (size_t)(dn * 512 + 1 * 256 + t) * 8, &lds[nxt + (1 * 256 + w * 64) * 8]);
        gload16(bseg + (size_t)(dn * 512 + 0 * 256 + t) * 8, &lds[nxt + 4096 + (0 * 256 + w * 64) * 8]);
        gload16(bseg + (size_t)(dn * 512 + 1 * 256 + t) * 8, &lds[nxt + 4096 + (1 * 256 + w * 64) * 8]);

        short8v af[4], bf[4];
#pragma unroll
        for (int mt = 0; mt < 4; ++mt)
            af[mt] = *(const short8v*)&lds[cur + lk * 1024 + (wm * 64 + mt * 16 + l15) * 8];
#pragma unroll
        for (int nt = 0; nt < 4; ++nt)
            bf[nt] = *(const short8v*)&lds[cur + 4096 + lk * 1024 + (wn * 64 + nt * 16 + l15) * 8];

#pragma unroll
        for (int mt = 0; mt < 4; ++mt)
#pragma unroll
            for (int nt = 0; nt < 4; ++nt)
                acc[mt][nt] = __builtin_amdgcn_mfma_f32_16x16x32_bf16(af[mt], bf[nt], acc[mt][nt], 0, 0, 0);

        __syncthreads();
    }

    // ---- epilogue: v = -2*dot + sc ; per-token tile-min ; candidates <= min+MARGIN ----
    float scv[4];
#pragma unroll
    for (int nt = 0; nt < 4; ++nt) scv[nt] = sc[bn * 128 + wn * 64 + nt * 16 + l15];

#pragma unroll
    for (int mt = 0; mt < 4; ++mt)
#pragma unroll
        for (int nt = 0; nt < 4; ++nt)
#pragma unroll
            for (int r = 0; r < 4; ++r)
                acc[mt][nt][r] = fmaf(-2.0f, acc[mt][nt][r], scv[nt]);

#pragma unroll
    for (int mt = 0; mt < 4; ++mt)
#pragma unroll
        for (int r = 0; r < 4; ++r) {
            float m4 = fminf(fminf(acc[mt][0][r], acc[mt][1][r]),
                             fminf(acc[mt][2][r], acc[mt][3][r]));
            m4 = fminf(m4, __shfl_xor(m4, 1, 64));
            m4 = fminf(m4, __shfl_xor(m4, 2, 64));
            m4 = fminf(m4, __shfl_xor(m4, 4, 64));
            m4 = fminf(m4, __shfl_xor(m4, 8, 64));
            if (l15 == 0) {
                const int tok = wm * 64 + mt * 16 + lk * 4 + r;
                atomicMin(&minsh[tok], ordkey(m4));
            }
        }
    __syncthreads();

#pragma unroll
    for (int mt = 0; mt < 4; ++mt)
#pragma unroll
        for (int r = 0; r < 4; ++r) {
            const int tok = wm * 64 + mt * 16 + lk * 4 + r;
            const float tmn = fromkey(minsh[tok]) + MARGIN;
#pragma unroll
            for (int nt = 0; nt < 4; ++nt) {
                if (acc[mt][nt][r] <= tmn) {
                    unsigned p = atomicAdd(&cntsh[tok], 1u);
                    if (p < RCAP)
                        listsh[tok][p] = (unsigned short)(bn * 128 + wn * 64 + nt * 16 + l15);
                }
            }
        }
    __syncthreads();

    if (t < 128) {
        const unsigned* lw = (const unsigned*)&listsh[t][0];
        uint4 r0, r1;
        r0.x = __float_as_uint(fromkey(minsh[t]));
        r0.y = cntsh[t];
        r0.z = lw[0]; r0.w = lw[1];
        r1.x = lw[2]; r1.y = lw[3]; r1.z = lw[4]; r1.w = lw[5];
        char* rp = records + ((size_t)(bm * 128 + t) * 32 + bn) * 32;
        *(uint4*)rp = r0;
        *(uint4*)(rp + 16) = r1;
    }
}

// ---------------- stage 2: resolve (exact rescue, validated semantics) ----------------
__global__ __launch_bounds__(256)
void resolve_kernel(const float* __restrict__ inp, const float* __restrict__ cb,
                    const float* __restrict__ sc, const float* __restrict__ sxg,
                    const char* __restrict__ records, int* __restrict__ out_idx) {
    __shared__ unsigned long long keysh[64];
    const int t = threadIdx.x;
    const int tokl = t >> 2, q = t & 3;
    const int token = blockIdx.x * 64 + tokl;
    if (t < 64) keysh[t] = 0xFFFFFFFFFFFFFFFFull;
    __syncthreads();

    const char* rbase = records + (size_t)token * 32 * 32;
    float mn = __builtin_huge_valf();
#pragma unroll
    for (int i = 0; i < 8; ++i)
        mn = fminf(mn, *(const float*)(rbase + (size_t)(q * 8 + i) * 32));
    mn = fminf(mn, __shfl_xor(mn, 1, 64));
    mn = fminf(mn, __shfl_xor(mn, 2, 64));
    const float thr = mn + MARGIN;

    const float sxv = sxg[token];
    const float* xrow = inp + (size_t)token * D;

#pragma unroll 1
    for (int i = 0; i < 8; ++i) {
        const int tile = q * 8 + i;
        const char* rp = rbase + (size_t)tile * 32;
        const float tmn = *(const float*)rp;
        if (tmn <= thr) {
            const unsigned cnt = *(const unsigned*)(rp + 4);
            if (cnt <= RCAP) {
                const unsigned short* cs = (const unsigned short*)(rp + 8);
                for (unsigned j2 = 0; j2 < cnt; ++j2) {
                    const int code = cs[j2];
                    const float dot = exact_dot512(xrow, cb + (size_t)code * D);
                    const float tmp = sxv - 2.0f * dot;
                    const float v   = tmp + sc[code];
                    const unsigned long long key =
                        ((unsigned long long)__float_as_uint(v) << 32) | (unsigned)code;
                    atomicMin(&keysh[tokl], key);
                }
            } else {
                for (int c2 = 0; c2 < 128; ++c2) {
                    const int code = tile * 128 + c2;
                    const float dot = exact_dot512(xrow, cb + (size_t)code * D);
                    const float tmp = sxv - 2.0f * dot;
                    const float v   = tmp + sc[code];
                    const unsigned long long key =
                        ((unsigned long long)__float_as_uint(v) << 32) | (unsigned)code;
                    atomicMin(&keysh[tokl], key);
                }
            }
        }
    }
    __syncthreads();
    if (t < 64) out_idx[blockIdx.x * 64 + t] = (int)(keysh[t] & 0xFFFFFFFFull);
}

// ---------------- gather: bit-exact codebook row copy ----------------
__global__ __launch_bounds__(256)
void gather_kernel(const float* __restrict__ cb, const int* __restrict__ idx,
                   float* __restrict__ out) {
    const int m0 = blockIdx.x * 64;
    __shared__ int bidx[64];
    if (threadIdx.x < 64) bidx[threadIdx.x] = idx[m0 + threadIdx.x];
    __syncthreads();
    for (int q = threadIdx.x; q < 64 * (D / 4); q += 256) {
        const int r = q >> 7;
        const int c = (q & 127) * 4;
        *(float4*)(out + (size_t)(m0 + r) * D + c) = *(const float4*)(cb + (size_t)bidx[r] * D + c);
    }
}

// ================= LEGACY (round-1 passing kernel, fallback) ==========
__global__ __launch_bounds__(256)
void vq_kernel(const float* __restrict__ inp, const float* __restrict__ cb,
               const float* __restrict__ sc, float* __restrict__ out) {
    __shared__ __align__(16) float As[BD_LEG][BM + PAD];
    __shared__ __align__(16) float Bs[BD_LEG][BN + PAD];
    __shared__ float sxl[BM];
    __shared__ float scs[BN];
    __shared__ int   bidx[BM];

    const int t  = threadIdx.x;
    const int m0 = blockIdx.x * BM;
    const int tm = t >> 4;
    const int tn = t & 15;
    const float FINF = __builtin_huge_valf();

    {
        const int r = t >> 2, p = t & 3;
        const float* row = inp + (size_t)(m0 + r) * D + p * 128;
        float s = 0.0f;
#pragma unroll
        for (int i = 0; i < 32; ++i) {
            float4 v = *(const float4*)(row + i * 4);
            s = fmaf(v.x, v.x, s); s = fmaf(v.y, v.y, s);
            s = fmaf(v.z, v.z, s); s = fmaf(v.w, v.w, s);
        }
        s += __shfl_xor(s, 1, 64);
        s += __shfl_xor(s, 2, 64);
        if (p == 0) sxl[r] = s;
    }
    __syncthreads();

    float sxm[4];
#pragma unroll
    for (int i = 0; i < 4; ++i) sxm[i] = sxl[tm * 4 + i];

    float runv[4] = {FINF, FINF, FINF, FINF};
    int   runi[4] = {0, 0, 0, 0};
    const int dq = (t & 7) << 2;
    const int mr = t >> 3;

#pragma unroll 1
    for (int kb = 0; kb < K; kb += BN) {
        __syncthreads();
        if (t < BN) scs[t] = sc[kb + t];

        float accl[4][4];
#pragma unroll
        for (int i = 0; i < 4; ++i)
#pragma unroll
            for (int j = 0; j < 4; ++j) accl[i][j] = 0.0f;

#pragma unroll 1
        for (int db = 0; db < D; db += BD_LEG) {
            const float* ap = inp + (size_t)(m0 + mr) * D + db + dq;
            const float* bp = cb  + (size_t)(kb + mr) * D + db + dq;
            float4 av0 = *(const float4*)ap;
            float4 av1 = *(const float4*)(ap + (size_t)32 * D);
            float4 bv0 = *(const float4*)bp;
            float4 bv1 = *(const float4*)(bp + (size_t)32 * D);
            __syncthreads();
            As[dq + 0][mr] = av0.x; As[dq + 1][mr] = av0.y;
            As[dq + 2][mr] = av0.z; As[dq + 3][mr] = av0.w;
            As[dq + 0][mr + 32] = av1.x; As[dq + 1][mr + 32] = av1.y;
            As[dq + 2][mr + 32] = av1.z; As[dq + 3][mr + 32] = av1.w;
            Bs[dq + 0][mr] = bv0.x; Bs[dq + 1][mr] = bv0.y;
            Bs[dq + 2][mr] = bv0.z; Bs[dq + 3][mr] = bv0.w;
            Bs[dq + 0][mr + 32] = bv1.x; Bs[dq + 1][mr + 32] = bv1.y;
            Bs[dq + 2][mr + 32] = bv1.z; Bs[dq + 3][mr + 32] = bv1.w;
            __syncthreads();
#pragma unroll
            for (int d = 0; d < BD_LEG; ++d) {
                const float4 a = *(const float4*)(&As[d][tm * 4]);
                const float4 b = *(const float4*)(&Bs[d][tn * 4]);
                float af[4] = {a.x, a.y, a.z, a.w};
                float bf[4] = {b.x, b.y, b.z, b.w};
#pragma unroll
                for (int i = 0; i < 4; ++i)
#pragma unroll
                    for (int j = 0; j < 4; ++j)
                        accl[i][j] = fmaf(af[i], bf[j], accl[i][j]);
            }
        }
#pragma unroll
        for (int i = 0; i < 4; ++i) {
            float bv = FINF;
            int   bi = 0x7fffffff;
#pragma unroll
            for (int j = 0; j < 4; ++j) {
                const float p = accl[i][j];
                const float tmp = sxm[i] - 2.0f * p;
                const float v   = tmp + scs[tn * 4 + j];
                const int  idx  = kb + tn * 4 + j;
                if (v < bv) { bv = v; bi = idx; }
            }
#pragma unroll
            for (int off = 1; off < 16; off <<= 1) {
                const float ov = __shfl_xor(bv, off, 64);
                const int   oi = __shfl_xor(bi, off, 64);
                if (ov < bv || (ov == bv && oi < bi)) { bv = ov; bi = oi; }
            }
            if (bv < runv[i]) { runv[i] = bv; runi[i] = bi; }
        }
    }
    if (tn == 0) {
#pragma unroll
        for (int i = 0; i < 4; ++i) bidx[tm * 4 + i] = runi[i];
    }
    __syncthreads();
#pragma unroll 1
    for (int q = t; q < BM * (D / 4); q += 256) {
        const int r = q >> 7;
        const int c = (q & 127) * 4;
        const float4 v = *(const float4*)(cb + (size_t)bidx[r] * D + c);
        *(float4*)(out + (size_t)(m0 + r) * D + c) = v;
    }
}

extern "C" void kernel_launch(void* const* d_in, const int* in_sizes, int n_in,
                              void* d_out, int out_size, void* d_ws, size_t ws_size,
                              hipStream_t stream) {
    const float* inp = (const float*)d_in[0];
    const float* cb  = (const float*)d_in[1];
    float* out = (float*)d_out;
    float* sc  = (float*)d_ws;
    const int tokens = in_sizes[0] / D;     // 32768

    const bool fast = (ws_size >= WS_NEED) && (tokens % 128 == 0) &&
                      (in_sizes[1] == K * D) &&
                      ((size_t)out_size * 4 >= (size_t)tokens * D * 2 + (size_t)tokens * 32 * 32);

    if (fast) {
        float* sxg = (float*)((char*)d_ws + SX_OFF);
        int*   idx = (int*)((char*)d_ws + IDX_OFF);
        unsigned short* cbp = (unsigned short*)((char*)d_ws + CBP_OFF);
        unsigned short* ap  = (unsigned short*)d_out;                       // 33.5 MB scratch
        char* records = (char*)d_out + (size_t)tokens * D * 2;              // 33.5 MB scratch

        sc_kernel<<<K / 4, 256, 0, stream>>>(cb, sc);
        sx_kernel<<<tokens / 64, 256, 0, stream>>>(inp, sxg);
        cvt_perm<<<(K * D / 8) / 256, 256, 0, stream>>>(cb, cbp);
        cvt_perm<<<(tokens * D / 8) / 256, 256, 0, stream>>>(inp, ap);
        score_kernel<<<(tokens / 128) * 32, 256, 0, stream>>>(ap, cbp, sc, records);
        resolve_kernel<<<tokens / 64, 256, 0, stream>>>(inp, cb, sc, sxg, records, idx);
        gather_kernel<<<tokens / 64, 256, 0, stream>>>(cb, idx, out);
    } else {
        sc_kernel<<<K / 4, 256, 0, stream>>>(cb, sc);
        vq_kernel<<<tokens / BM, 256, 0, stream>>>(inp, cb, sc, out);
    }
}

// Round 7
// 433.370 us; speedup vs baseline: 3.3113x; 1.4483x over previous
//
#include <hip/hip_runtime.h>
#include <math.h>

// BagOfConcepts: inp [8,4096,512] f32, codebook [4096,512] f32
constexpr int D  = 512;
constexpr int K  = 4096;
constexpr int BM = 64;
constexpr int BN = 64;
constexpr int BD_LEG = 32;
constexpr int PAD = 4;

#define MARGIN 2.5e-3f     // >= W + 2E (deterministic Cauchy-Schwarz bound ~2.4e-3)
constexpr int RCAP = 12;   // codes per (token,tile) record
constexpr unsigned CAPQ = 8388608u;   // queue capacity (fits ap region: 32 MB)

typedef short short8v __attribute__((ext_vector_type(8)));
typedef float f32x4   __attribute__((ext_vector_type(4)));

// ws layout (fast path)
constexpr size_t SC_OFF   = 0;                          // 4096 f32
constexpr size_t SX_OFF   = 16384;                      // 32768 f32
constexpr size_t KEYS_OFF = SX_OFF + 131072;            // 32768 u64 = 256 KB
constexpr size_t QCNT_OFF = KEYS_OFF + 262144;          // 1 u32 (+pad)
constexpr size_t CBP_OFF  = QCNT_OFF + 4096;            // 4096*512 u16 perm
constexpr size_t WS_NEED  = CBP_OFF + (size_t)K * D * 2;    // ~4.6 MB

__device__ inline unsigned short rne_bf16(float x) {
    unsigned u = __float_as_uint(x);
    return (unsigned short)((u + 0x7FFFu + ((u >> 16) & 1u)) >> 16);
}
__device__ inline unsigned ordkey(float f) {            // monotone f32 -> u32
    unsigned u = __float_as_uint(f);
    return (u & 0x80000000u) ? ~u : (u | 0x80000000u);
}
__device__ inline float fromkey(unsigned k) {
    unsigned u = (k & 0x80000000u) ? (k ^ 0x80000000u) : ~k;
    return __uint_as_float(u);
}
__device__ inline void gload16(const void* g, void* l) {
    __builtin_amdgcn_global_load_lds(
        (const __attribute__((address_space(1))) unsigned*)g,
        (__attribute__((address_space(3))) unsigned*)l, 16, 0, 0);
}

// ---------------- sc: s_c[k] = sum_d cb[k][d]^2 (UNCHANGED, validated) ----------------
__global__ __launch_bounds__(256)
void sc_kernel(const float* __restrict__ cb, float* __restrict__ sc) {
    const int row  = blockIdx.x * 4 + (threadIdx.x >> 6);
    const int lane = threadIdx.x & 63;
    const float* r = cb + (size_t)row * D + lane * 8;
    float4 v0 = *(const float4*)r;
    float4 v1 = *(const float4*)(r + 4);
    float s = v0.x * v0.x;
    s += v0.y * v0.y; s += v0.z * v0.z; s += v0.w * v0.w;
    s += v1.x * v1.x; s += v1.y * v1.y; s += v1.z * v1.z; s += v1.w * v1.w;
#pragma unroll
    for (int off = 1; off < 64; off <<= 1) s += __shfl_xor(s, off, 64);
    if (lane == 0) sc[row] = s;
}

// ---------------- sx: BIT-IDENTICAL arithmetic to validated prologue ----------------
__global__ __launch_bounds__(256)
void sx_kernel(const float* __restrict__ inp, float* __restrict__ sxg) {
    const int t = threadIdx.x;
    const int m0 = blockIdx.x * 64;
    const int r = t >> 2, p = t & 3;
    const float* row = inp + (size_t)(m0 + r) * D + p * 128;
    float s = 0.0f;
#pragma unroll
    for (int i = 0; i < 32; ++i) {
        float4 v = *(const float4*)(row + i * 4);
        s = fmaf(v.x, v.x, s); s = fmaf(v.y, v.y, s);
        s = fmaf(v.z, v.z, s); s = fmaf(v.w, v.w, s);
    }
    s += __shfl_xor(s, 1, 64);
    s += __shfl_xor(s, 2, 64);
    if (p == 0) sxg[m0 + r] = s;
}

// ------------- permute+convert f32 -> bf16 in LDS-image order (UNCHANGED) -------------
__global__ __launch_bounds__(256)
void cvt_perm(const float* __restrict__ src, unsigned short* __restrict__ dst) {
    const int s   = blockIdx.x * 256 + threadIdx.x;
    const int tile = s >> 13;
    const int db  = (s >> 9) & 15;
    const int j   = (s >> 7) & 3;
    const int row = s & 127;
    const float* sp = src + (size_t)(tile * 128 + row) * D + db * 32 + j * 8;
    float4 v0 = *(const float4*)sp;
    float4 v1 = *(const float4*)(sp + 4);
    float xs[8] = {v0.x, v0.y, v0.z, v0.w, v1.x, v1.y, v1.z, v1.w};
    union { short8v v; unsigned short u[8]; } H;
#pragma unroll
    for (int i = 0; i < 8; ++i) H.u[i] = rne_bf16(xs[i]);
    *(short8v*)(dst + (size_t)s * 8) = H.v;
}

// ---------------- exact sequential dot (bit-identical to validated path) ----------------
__device__ float exact_dot512(const float* __restrict__ x, const float* __restrict__ c) {
    float s = 0.0f;
#pragma unroll 4
    for (int i = 0; i < 128; ++i) {
        const float4 xv = *(const float4*)(x + i * 4);
        const float4 cv = *(const float4*)(c + i * 4);
        s = fmaf(xv.x, cv.x, s); s = fmaf(xv.y, cv.y, s);
        s = fmaf(xv.z, cv.z, s); s = fmaf(xv.w, cv.w, s);
    }
    return s;
}

// ---------------- stage 1: 128x128 tile GEMM + per-tile argmin records (UNCHANGED) ----
__global__ __launch_bounds__(256)
void score_kernel(const unsigned short* __restrict__ a_perm,
                  const unsigned short* __restrict__ b_perm,
                  const float* __restrict__ sc,
                  char* __restrict__ records) {
    __shared__ __align__(16) unsigned short lds[16384];   // 32 KB: [buf:2][8192 halves]
    __shared__ unsigned minsh[128];
    __shared__ unsigned cntsh[128];
    __shared__ unsigned short listsh[128][RCAP];

    const int t    = threadIdx.x;
    const int lane = t & 63;
    const int w    = t >> 6;
    const int wm   = w >> 1, wn = w & 1;
    const int l15  = lane & 15;
    const int lk   = lane >> 4;
    const int bm   = blockIdx.x >> 5;
    const int bn   = blockIdx.x & 31;

    const unsigned short* aseg = a_perm + (size_t)bm * (16 * 4096);
    const unsigned short* bseg = b_perm + (size_t)bn * (16 * 4096);

    if (t < 128) { minsh[t] = 0xFFFFFFFFu; cntsh[t] = 0u; }

    gload16(aseg + (size_t)(0 * 512 + 0 * 256 + t) * 8, &lds[(0 * 256 + w * 64) * 8]);
    gload16(aseg + (size_t)(0 * 512 + 1 * 256 + t) * 8, &lds[(1 * 256 + w * 64) * 8]);
    gload16(bseg + (size_t)(0 * 512 + 0 * 256 + t) * 8, &lds[4096 + (0 * 256 + w * 64) * 8]);
    gload16(bseg + (size_t)(0 * 512 + 1 * 256 + t) * 8, &lds[4096 + (1 * 256 + w * 64) * 8]);
    __syncthreads();

    f32x4 acc[4][4];
#pragma unroll
    for (int i = 0; i < 4; ++i)
#pragma unroll
        for (int j = 0; j < 4; ++j) acc[i][j] = f32x4{0.f, 0.f, 0.f, 0.f};

#pragma unroll 1
    for (int db = 0; db < 16; ++db) {
        const int cur = (db & 1) * 8192;
        const int nxt = 8192 - cur;
        const int dn  = (db + 1) & 15;

        gload16(aseg + (size_t)(dn * 512 + 0 * 256 + t) * 8, &lds[nxt + (0 * 256 + w * 64) * 8]);
        gload16(aseg + (size_t)(dn * 512 + 1 * 256 + t) * 8, &lds[nxt + (1 * 256 + w * 64) * 8]);
        gload16(bseg + (size_t)(dn * 512 + 0 * 256 + t) * 8, &lds[nxt + 4096 + (0 * 256 + w * 64) * 8]);
        gload16(bseg + (size_t)(dn * 512 + 1 * 256 + t) * 8, &lds[nxt + 4096 + (1 * 256 + w * 64) * 8]);

        short8v af[4], bf[4];
#pragma unroll
        for (int mt = 0; mt < 4; ++mt)
            af[mt] = *(const short8v*)&lds[cur + lk * 1024 + (wm * 64 + mt * 16 + l15) * 8];
#pragma unroll
        for (int nt = 0; nt < 4; ++nt)
            bf[nt] = *(const short8v*)&lds[cur + 4096 + lk * 1024 + (wn * 64 + nt * 16 + l15) * 8];

#pragma unroll
        for (int mt = 0; mt < 4; ++mt)
#pragma unroll
            for (int nt = 0; nt < 4; ++nt)
                acc[mt][nt] = __builtin_amdgcn_mfma_f32_16x16x32_bf16(af[mt], bf[nt], acc[mt][nt], 0, 0, 0);

        __syncthreads();
    }

    float scv[4];
#pragma unroll
    for (int nt = 0; nt < 4; ++nt) scv[nt] = sc[bn * 128 + wn * 64 + nt * 16 + l15];

#pragma unroll
    for (int mt = 0; mt < 4; ++mt)
#pragma unroll
        for (int nt = 0; nt < 4; ++nt)
#pragma unroll
            for (int r = 0; r < 4; ++r)
                acc[mt][nt][r] = fmaf(-2.0f, acc[mt][nt][r], scv[nt]);

#pragma unroll
    for (int mt = 0; mt < 4; ++mt)
#pragma unroll
        for (int r = 0; r < 4; ++r) {
            float m4 = fminf(fminf(acc[mt][0][r], acc[mt][1][r]),
                             fminf(acc[mt][2][r], acc[mt][3][r]));
            m4 = fminf(m4, __shfl_xor(m4, 1, 64));
            m4 = fminf(m4, __shfl_xor(m4, 2, 64));
            m4 = fminf(m4, __shfl_xor(m4, 4, 64));
            m4 = fminf(m4, __shfl_xor(m4, 8, 64));
            if (l15 == 0) {
                const int tok = wm * 64 + mt * 16 + lk * 4 + r;
                atomicMin(&minsh[tok], ordkey(m4));
            }
        }
    __syncthreads();

#pragma unroll
    for (int mt = 0; mt < 4; ++mt)
#pragma unroll
        for (int r = 0; r < 4; ++r) {
            const int tok = wm * 64 + mt * 16 + lk * 4 + r;
            const float tmn = fromkey(minsh[tok]) + MARGIN;
#pragma unroll
            for (int nt = 0; nt < 4; ++nt) {
                if (acc[mt][nt][r] <= tmn) {
                    unsigned p = atomicAdd(&cntsh[tok], 1u);
                    if (p < RCAP)
                        listsh[tok][p] = (unsigned short)(bn * 128 + wn * 64 + nt * 16 + l15);
                }
            }
        }
    __syncthreads();

    if (t < 128) {
        const unsigned* lw = (const unsigned*)&listsh[t][0];
        uint4 r0, r1;
        r0.x = __float_as_uint(fromkey(minsh[t]));
        r0.y = cntsh[t];
        r0.z = lw[0]; r0.w = lw[1];
        r1.x = lw[2]; r1.y = lw[3]; r1.z = lw[4]; r1.w = lw[5];
        char* rp = records + ((size_t)(bm * 128 + t) * 32 + bn) * 32;
        *(uint4*)rp = r0;
        *(uint4*)(rp + 16) = r1;
    }
}

// ---------------- stage 2a: compact candidates into a flat queue ----------------
// 1 thread per token. Entry = token<<12 | code (27 bits). One atomicAdd per token.
__global__ __launch_bounds__(256)
void compact_kernel(const char* __restrict__ records,
                    unsigned long long* __restrict__ keysg,
                    unsigned* __restrict__ qcnt,
                    unsigned* __restrict__ queue) {
    const int token = blockIdx.x * 256 + threadIdx.x;
    keysg[token] = 0xFFFFFFFFFFFFFFFFull;

    const char* rbase = records + (size_t)token * 32 * 32;
    float mn = __builtin_huge_valf();
#pragma unroll
    for (int i = 0; i < 32; ++i)
        mn = fminf(mn, *(const float*)(rbase + (size_t)i * 32));
    const float thr = mn + MARGIN;

    // count
    unsigned my = 0;
#pragma unroll 1
    for (int i = 0; i < 32; ++i) {
        const char* rp = rbase + (size_t)i * 32;
        if (*(const float*)rp <= thr) {
            const unsigned cnt = *(const unsigned*)(rp + 4);
            my += (cnt <= RCAP) ? cnt : 128u;
        }
    }
    unsigned pos = atomicAdd(qcnt, my);
    // write
#pragma unroll 1
    for (int i = 0; i < 32; ++i) {
        const char* rp = rbase + (size_t)i * 32;
        if (*(const float*)rp <= thr) {
            const unsigned cnt = *(const unsigned*)(rp + 4);
            if (cnt <= RCAP) {
                const unsigned short* cs = (const unsigned short*)(rp + 8);
                for (unsigned j = 0; j < cnt; ++j) {
                    if (pos < CAPQ) queue[pos] = ((unsigned)token << 12) | cs[j];
                    ++pos;
                }
            } else {
                for (int c2 = 0; c2 < 128; ++c2) {
                    if (pos < CAPQ) queue[pos] = ((unsigned)token << 12) | (unsigned)(i * 128 + c2);
                    ++pos;
                }
            }
        }
    }
}

// ---------------- stage 2b: exec — one lane per candidate, exact rescue ----------------
__global__ __launch_bounds__(256)
void exec_kernel(const float* __restrict__ inp, const float* __restrict__ cb,
                 const float* __restrict__ sc, const float* __restrict__ sxg,
                 const unsigned* __restrict__ qcnt, const unsigned* __restrict__ queue,
                 unsigned long long* __restrict__ keysg) {
    unsigned total = *qcnt;
    if (total > CAPQ) total = CAPQ;
    const unsigned stride = gridDim.x * 256;
    for (unsigned i = blockIdx.x * 256 + threadIdx.x; i < total; i += stride) {
        const unsigned e = queue[i];
        const int token = e >> 12;
        const int code  = e & 4095;
        const float dot = exact_dot512(inp + (size_t)token * D, cb + (size_t)code * D);
        const float tmp = sxg[token] - 2.0f * dot;   // -2*dot exact => contraction-immune
        const float v   = tmp + sc[code];
        const unsigned long long key =
            ((unsigned long long)__float_as_uint(v) << 32) | (unsigned)code;
        atomicMin(&keysg[token], key);
    }
}

// ---------------- stage 2c: safety — full exact scan iff queue overflowed (never) ------
__global__ __launch_bounds__(256)
void safety_kernel(const float* __restrict__ inp, const float* __restrict__ cb,
                   const float* __restrict__ sc, const float* __restrict__ sxg,
                   const unsigned* __restrict__ qcnt,
                   unsigned long long* __restrict__ keysg) {
    if (*qcnt <= CAPQ) return;
    const int t = threadIdx.x;
    const int m0 = blockIdx.x * 64;
#pragma unroll 1
    for (int tok = 0; tok < 64; ++tok) {
        const int token = m0 + tok;
        const float sxv = sxg[token];
        const float* xrow = inp + (size_t)token * D;
        for (int code = t; code < K; code += 256) {
            const float dot = exact_dot512(xrow, cb + (size_t)code * D);
            const float tmp = sxv - 2.0f * dot;
            const float v   = tmp + sc[code];
            const unsigned long long key =
                ((unsigned long long)__float_as_uint(v) << 32) | (unsigned)code;
            atomicMin(&keysg[token], key);
        }
    }
}

// ---------------- gather: bit-exact codebook row copy (reads keys directly) ------------
__global__ __launch_bounds__(256)
void gather_kernel(const float* __restrict__ cb,
                   const unsigned long long* __restrict__ keysg,
                   float* __restrict__ out) {
    const int m0 = blockIdx.x * 64;
    __shared__ int bidx[64];
    if (threadIdx.x < 64) bidx[threadIdx.x] = (int)(keysg[m0 + threadIdx.x] & 0xFFFFFFFFull);
    __syncthreads();
    for (int q = threadIdx.x; q < 64 * (D / 4); q += 256) {
        const int r = q >> 7;
        const int c = (q & 127) * 4;
        *(float4*)(out + (size_t)(m0 + r) * D + c) = *(const float4*)(cb + (size_t)bidx[r] * D + c);
    }
}

// ================= LEGACY (round-1 passing kernel, fallback) ==========
__global__ __launch_bounds__(256)
void vq_kernel(const float* __restrict__ inp, const float* __restrict__ cb,
               const float* __restrict__ sc, float* __restrict__ out) {
    __shared__ __align__(16) float As[BD_LEG][BM + PAD];
    __shared__ __align__(16) float Bs[BD_LEG][BN + PAD];
    __shared__ float sxl[BM];
    __shared__ float scs[BN];
    __shared__ int   bidx[BM];

    const int t  = threadIdx.x;
    const int m0 = blockIdx.x * BM;
    const int tm = t >> 4;
    const int tn = t & 15;
    const float FINF = __builtin_huge_valf();

    {
        const int r = t >> 2, p = t & 3;
        const float* row = inp + (size_t)(m0 + r) * D + p * 128;
        float s = 0.0f;
#pragma unroll
        for (int i = 0; i < 32; ++i) {
            float4 v = *(const float4*)(row + i * 4);
            s = fmaf(v.x, v.x, s); s = fmaf(v.y, v.y, s);
            s = fmaf(v.z, v.z, s); s = fmaf(v.w, v.w, s);
        }
        s += __shfl_xor(s, 1, 64);
        s += __shfl_xor(s, 2, 64);
        if (p == 0) sxl[r] = s;
    }
    __syncthreads();

    float sxm[4];
#pragma unroll
    for (int i = 0; i < 4; ++i) sxm[i] = sxl[tm * 4 + i];

    float runv[4] = {FINF, FINF, FINF, FINF};
    int   runi[4] = {0, 0, 0, 0};
    const int dq = (t & 7) << 2;
    const int mr = t >> 3;

#pragma unroll 1
    for (int kb = 0; kb < K; kb += BN) {
        __syncthreads();
        if (t < BN) scs[t] = sc[kb + t];

        float accl[4][4];
#pragma unroll
        for (int i = 0; i < 4; ++i)
#pragma unroll
            for (int j = 0; j < 4; ++j) accl[i][j] = 0.0f;

#pragma unroll 1
        for (int db = 0; db < D; db += BD_LEG) {
            const float* ap = inp + (size_t)(m0 + mr) * D + db + dq;
            const float* bp = cb  + (size_t)(kb + mr) * D + db + dq;
            float4 av0 = *(const float4*)ap;
            float4 av1 = *(const float4*)(ap + (size_t)32 * D);
            float4 bv0 = *(const float4*)bp;
            float4 bv1 = *(const float4*)(bp + (size_t)32 * D);
            __syncthreads();
            As[dq + 0][mr] = av0.x; As[dq + 1][mr] = av0.y;
            As[dq + 2][mr] = av0.z; As[dq + 3][mr] = av0.w;
            As[dq + 0][mr + 32] = av1.x; As[dq + 1][mr + 32] = av1.y;
            As[dq + 2][mr + 32] = av1.z; As[dq + 3][mr + 32] = av1.w;
            Bs[dq + 0][mr] = bv0.x; Bs[dq + 1][mr] = bv0.y;
            Bs[dq + 2][mr] = bv0.z; Bs[dq + 3][mr] = bv0.w;
            Bs[dq + 0][mr + 32] = bv1.x; Bs[dq + 1][mr + 32] = bv1.y;
            Bs[dq + 2][mr + 32] = bv1.z; Bs[dq + 3][mr + 32] = bv1.w;
            __syncthreads();
#pragma unroll
            for (int d = 0; d < BD_LEG; ++d) {
                const float4 a = *(const float4*)(&As[d][tm * 4]);
                const float4 b = *(const float4*)(&Bs[d][tn * 4]);
                float af[4] = {a.x, a.y, a.z, a.w};
                float bf[4] = {b.x, b.y, b.z, b.w};
#pragma unroll
                for (int i = 0; i < 4; ++i)
#pragma unroll
                    for (int j = 0; j < 4; ++j)
                        accl[i][j] = fmaf(af[i], bf[j], accl[i][j]);
            }
        }
#pragma unroll
        for (int i = 0; i < 4; ++i) {
            float bv = FINF;
            int   bi = 0x7fffffff;
#pragma unroll
            for (int j = 0; j < 4; ++j) {
                const float p = accl[i][j];
                const float tmp = sxm[i] - 2.0f * p;
                const float v   = tmp + scs[tn * 4 + j];
                const int  idx  = kb + tn * 4 + j;
                if (v < bv) { bv = v; bi = idx; }
            }
#pragma unroll
            for (int off = 1; off < 16; off <<= 1) {
                const float ov = __shfl_xor(bv, off, 64);
                const int   oi = __shfl_xor(bi, off, 64);
                if (ov < bv || (ov == bv && oi < bi)) { bv = ov; bi = oi; }
            }
            if (bv < runv[i]) { runv[i] = bv; runi[i] = bi; }
        }
    }
    if (tn == 0) {
#pragma unroll
        for (int i = 0; i < 4; ++i) bidx[tm * 4 + i] = runi[i];
    }
    __syncthreads();
#pragma unroll 1
    for (int q = t; q < BM * (D / 4); q += 256) {
        const int r = q >> 7;
        const int c = (q & 127) * 4;
        const float4 v = *(const float4*)(cb + (size_t)bidx[r] * D + c);
        *(float4*)(out + (size_t)(m0 + r) * D + c) = v;
    }
}

extern "C" void kernel_launch(void* const* d_in, const int* in_sizes, int n_in,
                              void* d_out, int out_size, void* d_ws, size_t ws_size,
                              hipStream_t stream) {
    const float* inp = (const float*)d_in[0];
    const float* cb  = (const float*)d_in[1];
    float* out = (float*)d_out;
    float* sc  = (float*)d_ws;
    const int tokens = in_sizes[0] / D;     // 32768

    const bool fast = (ws_size >= WS_NEED) && (tokens % 256 == 0) &&
                      (in_sizes[1] == K * D) &&
                      ((size_t)out_size * 4 >= (size_t)tokens * D * 2 + (size_t)tokens * 32 * 32);

    if (fast) {
        float* sxg = (float*)((char*)d_ws + SX_OFF);
        unsigned long long* keysg = (unsigned long long*)((char*)d_ws + KEYS_OFF);
        unsigned* qcnt = (unsigned*)((char*)d_ws + QCNT_OFF);
        unsigned short* cbp = (unsigned short*)((char*)d_ws + CBP_OFF);
        unsigned short* ap  = (unsigned short*)d_out;                       // 33.5 MB scratch
        char* records = (char*)d_out + (size_t)tokens * D * 2;              // 33.5 MB scratch
        unsigned* queue = (unsigned*)d_out;                                 // overlays ap (dead after score)

        hipMemsetAsync(qcnt, 0, sizeof(unsigned), stream);
        sc_kernel<<<K / 4, 256, 0, stream>>>(cb, sc);
        sx_kernel<<<tokens / 64, 256, 0, stream>>>(inp, sxg);
        cvt_perm<<<(K * D / 8) / 256, 256, 0, stream>>>(cb, cbp);
        cvt_perm<<<(tokens * D / 8) / 256, 256, 0, stream>>>(inp, ap);
        score_kernel<<<(tokens / 128) * 32, 256, 0, stream>>>(ap, cbp, sc, records);
        compact_kernel<<<tokens / 256, 256, 0, stream>>>(records, keysg, qcnt, queue);
        exec_kernel<<<2048, 256, 0, stream>>>(inp, cb, sc, sxg, qcnt, queue, keysg);
        safety_kernel<<<tokens / 64, 256, 0, stream>>>(inp, cb, sc, sxg, qcnt, keysg);
        gather_kernel<<<tokens / 64, 256, 0, stream>>>(cb, keysg, out);
    } else {
        sc_kernel<<<K / 4, 256, 0, stream>>>(cb, sc);
        vq_kernel<<<tokens / BM, 256, 0, stream>>>(inp, cb, sc, out);
    }
}

// Round 8
// 412.114 us; speedup vs baseline: 3.4821x; 1.0516x over previous
//
#include <hip/hip_runtime.h>
#include <math.h>

// BagOfConcepts: inp [8,4096,512] f32, codebook [4096,512] f32
constexpr int D  = 512;
constexpr int K  = 4096;
constexpr int BM = 64;
constexpr int BN = 64;
constexpr int BD_LEG = 32;
constexpr int PAD = 4;

#define MARGIN 2.5e-3f     // >= W + 2E (deterministic bound); validated r6/r7
constexpr int RCAP = 12;   // codes per (token,tile) record
constexpr unsigned CAPQ = 8388608u;   // queue capacity (fits ap region: 32 MB)

typedef short short8v __attribute__((ext_vector_type(8)));
typedef float f32x4   __attribute__((ext_vector_type(4)));

// ws layout (fast path)
constexpr size_t SC_OFF   = 0;                          // 4096 f32
constexpr size_t SX_OFF   = 16384;                      // 32768 f32
constexpr size_t KEYS_OFF = SX_OFF + 131072;            // 32768 u64 = 256 KB
constexpr size_t QCNT_OFF = KEYS_OFF + 262144;          // 1 u32 (+pad)
constexpr size_t CBP_OFF  = QCNT_OFF + 4096;            // 4096*512 u16 perm
constexpr size_t WS_NEED  = CBP_OFF + (size_t)K * D * 2;    // ~4.6 MB

__device__ inline unsigned short rne_bf16(float x) {
    unsigned u = __float_as_uint(x);
    return (unsigned short)((u + 0x7FFFu + ((u >> 16) & 1u)) >> 16);
}
__device__ inline unsigned ordkey(float f) {            // monotone f32 -> u32
    unsigned u = __float_as_uint(f);
    return (u & 0x80000000u) ? ~u : (u | 0x80000000u);
}
__device__ inline float fromkey(unsigned k) {
    unsigned u = (k & 0x80000000u) ? (k ^ 0x80000000u) : ~k;
    return __uint_as_float(u);
}
__device__ inline void gload16(const void* g, void* l) {
    __builtin_amdgcn_global_load_lds(
        (const __attribute__((address_space(1))) unsigned*)g,
        (__attribute__((address_space(3))) unsigned*)l, 16, 0, 0);
}

// ---------------- sc: s_c[k] = sum_d cb[k][d]^2 (UNCHANGED, validated) ----------------
__global__ __launch_bounds__(256)
void sc_kernel(const float* __restrict__ cb, float* __restrict__ sc) {
    const int row  = blockIdx.x * 4 + (threadIdx.x >> 6);
    const int lane = threadIdx.x & 63;
    const float* r = cb + (size_t)row * D + lane * 8;
    float4 v0 = *(const float4*)r;
    float4 v1 = *(const float4*)(r + 4);
    float s = v0.x * v0.x;
    s += v0.y * v0.y; s += v0.z * v0.z; s += v0.w * v0.w;
    s += v1.x * v1.x; s += v1.y * v1.y; s += v1.z * v1.z; s += v1.w * v1.w;
#pragma unroll
    for (int off = 1; off < 64; off <<= 1) s += __shfl_xor(s, off, 64);
    if (lane == 0) sc[row] = s;
}

// ---------------- sx: BIT-IDENTICAL arithmetic to validated prologue ----------------
__global__ __launch_bounds__(256)
void sx_kernel(const float* __restrict__ inp, float* __restrict__ sxg) {
    const int t = threadIdx.x;
    const int m0 = blockIdx.x * 64;
    const int r = t >> 2, p = t & 3;
    const float* row = inp + (size_t)(m0 + r) * D + p * 128;
    float s = 0.0f;
#pragma unroll
    for (int i = 0; i < 32; ++i) {
        float4 v = *(const float4*)(row + i * 4);
        s = fmaf(v.x, v.x, s); s = fmaf(v.y, v.y, s);
        s = fmaf(v.z, v.z, s); s = fmaf(v.w, v.w, s);
    }
    s += __shfl_xor(s, 1, 64);
    s += __shfl_xor(s, 2, 64);
    if (p == 0) sxg[m0 + r] = s;
}

// ------------- permute+convert f32 -> bf16 in LDS-image order (UNCHANGED) -------------
__global__ __launch_bounds__(256)
void cvt_perm(const float* __restrict__ src, unsigned short* __restrict__ dst) {
    const int s   = blockIdx.x * 256 + threadIdx.x;
    const int tile = s >> 13;
    const int db  = (s >> 9) & 15;
    const int j   = (s >> 7) & 3;
    const int row = s & 127;
    const float* sp = src + (size_t)(tile * 128 + row) * D + db * 32 + j * 8;
    float4 v0 = *(const float4*)sp;
    float4 v1 = *(const float4*)(sp + 4);
    float xs[8] = {v0.x, v0.y, v0.z, v0.w, v1.x, v1.y, v1.z, v1.w};
    union { short8v v; unsigned short u[8]; } H;
#pragma unroll
    for (int i = 0; i < 8; ++i) H.u[i] = rne_bf16(xs[i]);
    *(short8v*)(dst + (size_t)s * 8) = H.v;
}

// ---------------- exact sequential dot (bit-identical to validated path) ----------------
__device__ float exact_dot512(const float* __restrict__ x, const float* __restrict__ c) {
    float s = 0.0f;
#pragma unroll 4
    for (int i = 0; i < 128; ++i) {
        const float4 xv = *(const float4*)(x + i * 4);
        const float4 cv = *(const float4*)(c + i * 4);
        s = fmaf(xv.x, cv.x, s); s = fmaf(xv.y, cv.y, s);
        s = fmaf(xv.z, cv.z, s); s = fmaf(xv.w, cv.w, s);
    }
    return s;
}

// ---------------- stage 1: 128x128 tile GEMM + per-tile argmin records ----------------
// Restructured main loop (r8): unroll-by-2 (cur/nxt compile-time), peeled last staging,
// induction-variable global offsets, single per-thread LDS base + immediate offsets.
// Epilogue and record format UNCHANGED (validated r6/r7).
__global__ __launch_bounds__(256)
void score_kernel(const unsigned short* __restrict__ a_perm,
                  const unsigned short* __restrict__ b_perm,
                  const float* __restrict__ sc,
                  char* __restrict__ records) {
    __shared__ __align__(16) unsigned short lds[16384];   // 32 KB: [buf:2][8192 halves]
    __shared__ unsigned minsh[128];
    __shared__ unsigned cntsh[128];
    __shared__ unsigned short listsh[128][RCAP];

    const int t    = threadIdx.x;
    const int lane = t & 63;
    const int w    = t >> 6;
    const int wm   = w >> 1, wn = w & 1;
    const int l15  = lane & 15;
    const int lk   = lane >> 4;
    const int bm   = blockIdx.x >> 5;
    const int bn   = blockIdx.x & 31;

    // per-thread staging pointers (elements = halves); chunk c at +c*4096, q=1 at +2048
    const unsigned short* gA = a_perm + (size_t)bm * 65536 + (size_t)t * 8;
    const unsigned short* gB = b_perm + (size_t)bn * 65536 + (size_t)t * 8;

    if (t < 128) { minsh[t] = 0xFFFFFFFFu; cntsh[t] = 0u; }

    f32x4 acc[4][4];
#pragma unroll
    for (int i = 0; i < 4; ++i)
#pragma unroll
        for (int j = 0; j < 4; ++j) acc[i][j] = f32x4{0.f, 0.f, 0.f, 0.f};

    // stage(soff in halves, dbuf in {0,8192}): 4x gload16, wave-uniform LDS base
    auto STAGE = [&](int soff, int dbuf) {
        gload16(gA + soff,        &lds[dbuf + (0 * 256 + w * 64) * 8]);
        gload16(gA + soff + 2048, &lds[dbuf + (1 * 256 + w * 64) * 8]);
        gload16(gB + soff,        &lds[dbuf + 4096 + (0 * 256 + w * 64) * 8]);
        gload16(gB + soff + 2048, &lds[dbuf + 4096 + (1 * 256 + w * 64) * 8]);
    };

    // prologue: chunk 0 -> buf0
    STAGE(0, 0);
    __syncthreads();

    // per-thread LDS read base; all 16 ds_read_b128 = base + compile-time immediate
    const unsigned short* lb = &lds[lk * 1024 + l15 * 8];
    const int mbase = wm * 512;           // wave-uniform
    const int nbase = 4096 + wn * 512;

    auto COMPUTE = [&](int cur) {
        short8v af[4], bf[4];
#pragma unroll
        for (int mt = 0; mt < 4; ++mt)
            af[mt] = *(const short8v*)(lb + cur + mbase + mt * 128);
#pragma unroll
        for (int nt = 0; nt < 4; ++nt)
            bf[nt] = *(const short8v*)(lb + cur + nbase + nt * 128);
#pragma unroll
        for (int mt = 0; mt < 4; ++mt)
#pragma unroll
            for (int nt = 0; nt < 4; ++nt)
                acc[mt][nt] = __builtin_amdgcn_mfma_f32_16x16x32_bf16(af[mt], bf[nt], acc[mt][nt], 0, 0, 0);
    };

    int soff = 4096;   // next chunk to stage = chunk 1
#pragma unroll 1
    for (int p = 0; p < 8; ++p) {
        // even sub-iter: compute buf0 (chunk 2p), stage chunk 2p+1 -> buf1
        STAGE(soff, 8192); soff += 4096;
        COMPUTE(0);
        __syncthreads();
        // odd sub-iter: compute buf1 (chunk 2p+1), stage chunk 2p+2 -> buf0 (skip last)
        if (p < 7) { STAGE(soff, 0); soff += 4096; }
        COMPUTE(8192);
        __syncthreads();
    }

    // ---- epilogue: UNCHANGED (validated) ----
    float scv[4];
#pragma unroll
    for (int nt = 0; nt < 4; ++nt) scv[nt] = sc[bn * 128 + wn * 64 + nt * 16 + l15];

#pragma unroll
    for (int mt = 0; mt < 4; ++mt)
#pragma unroll
        for (int nt = 0; nt < 4; ++nt)
#pragma unroll
            for (int r = 0; r < 4; ++r)
                acc[mt][nt][r] = fmaf(-2.0f, acc[mt][nt][r], scv[nt]);

#pragma unroll
    for (int mt = 0; mt < 4; ++mt)
#pragma unroll
        for (int r = 0; r < 4; ++r) {
            float m4 = fminf(fminf(acc[mt][0][r], acc[mt][1][r]),
                             fminf(acc[mt][2][r], acc[mt][3][r]));
            m4 = fminf(m4, __shfl_xor(m4, 1, 64));
            m4 = fminf(m4, __shfl_xor(m4, 2, 64));
            m4 = fminf(m4, __shfl_xor(m4, 4, 64));
            m4 = fminf(m4, __shfl_xor(m4, 8, 64));
            if (l15 == 0) {
                const int tok = wm * 64 + mt * 16 + lk * 4 + r;
                atomicMin(&minsh[tok], ordkey(m4));
            }
        }
    __syncthreads();

#pragma unroll
    for (int mt = 0; mt < 4; ++mt)
#pragma unroll
        for (int r = 0; r < 4; ++r) {
            const int tok = wm * 64 + mt * 16 + lk * 4 + r;
            const float tmn = fromkey(minsh[tok]) + MARGIN;
#pragma unroll
            for (int nt = 0; nt < 4; ++nt) {
                if (acc[mt][nt][r] <= tmn) {
                    unsigned p = atomicAdd(&cntsh[tok], 1u);
                    if (p < RCAP)
                        listsh[tok][p] = (unsigned short)(bn * 128 + wn * 64 + nt * 16 + l15);
                }
            }
        }
    __syncthreads();

    if (t < 128) {
        const unsigned* lw = (const unsigned*)&listsh[t][0];
        uint4 r0, r1;
        r0.x = __float_as_uint(fromkey(minsh[t]));
        r0.y = cntsh[t];
        r0.z = lw[0]; r0.w = lw[1];
        r1.x = lw[2]; r1.y = lw[3]; r1.z = lw[4]; r1.w = lw[5];
        char* rp = records + ((size_t)(bm * 128 + t) * 32 + bn) * 32;
        *(uint4*)rp = r0;
        *(uint4*)(rp + 16) = r1;
    }
}

// ---------------- stage 2a: compact candidates into a flat queue (UNCHANGED) ----------
__global__ __launch_bounds__(256)
void compact_kernel(const char* __restrict__ records,
                    unsigned long long* __restrict__ keysg,
                    unsigned* __restrict__ qcnt,
                    unsigned* __restrict__ queue) {
    const int token = blockIdx.x * 256 + threadIdx.x;
    keysg[token] = 0xFFFFFFFFFFFFFFFFull;

    const char* rbase = records + (size_t)token * 32 * 32;
    float mn = __builtin_huge_valf();
#pragma unroll
    for (int i = 0; i < 32; ++i)
        mn = fminf(mn, *(const float*)(rbase + (size_t)i * 32));
    const float thr = mn + MARGIN;

    unsigned my = 0;
#pragma unroll 1
    for (int i = 0; i < 32; ++i) {
        const char* rp = rbase + (size_t)i * 32;
        if (*(const float*)rp <= thr) {
            const unsigned cnt = *(const unsigned*)(rp + 4);
            my += (cnt <= RCAP) ? cnt : 128u;
        }
    }
    unsigned pos = atomicAdd(qcnt, my);
#pragma unroll 1
    for (int i = 0; i < 32; ++i) {
        const char* rp = rbase + (size_t)i * 32;
        if (*(const float*)rp <= thr) {
            const unsigned cnt = *(const unsigned*)(rp + 4);
            if (cnt <= RCAP) {
                const unsigned short* cs = (const unsigned short*)(rp + 8);
                for (unsigned j = 0; j < cnt; ++j) {
                    if (pos < CAPQ) queue[pos] = ((unsigned)token << 12) | cs[j];
                    ++pos;
                }
            } else {
                for (int c2 = 0; c2 < 128; ++c2) {
                    if (pos < CAPQ) queue[pos] = ((unsigned)token << 12) | (unsigned)(i * 128 + c2);
                    ++pos;
                }
            }
        }
    }
}

// ---------------- stage 2b: exec — one lane per candidate, exact rescue (UNCHANGED) ----
__global__ __launch_bounds__(256)
void exec_kernel(const float* __restrict__ inp, const float* __restrict__ cb,
                 const float* __restrict__ sc, const float* __restrict__ sxg,
                 const unsigned* __restrict__ qcnt, const unsigned* __restrict__ queue,
                 unsigned long long* __restrict__ keysg) {
    unsigned total = *qcnt;
    if (total > CAPQ) total = CAPQ;
    const unsigned stride = gridDim.x * 256;
    for (unsigned i = blockIdx.x * 256 + threadIdx.x; i < total; i += stride) {
        const unsigned e = queue[i];
        const int token = e >> 12;
        const int code  = e & 4095;
        const float dot = exact_dot512(inp + (size_t)token * D, cb + (size_t)code * D);
        const float tmp = sxg[token] - 2.0f * dot;   // -2*dot exact => contraction-immune
        const float v   = tmp + sc[code];
        const unsigned long long key =
            ((unsigned long long)__float_as_uint(v) << 32) | (unsigned)code;
        atomicMin(&keysg[token], key);
    }
}

// ---------------- stage 2c: safety — full exact scan iff queue overflowed (UNCHANGED) --
__global__ __launch_bounds__(256)
void safety_kernel(const float* __restrict__ inp, const float* __restrict__ cb,
                   const float* __restrict__ sc, const float* __restrict__ sxg,
                   const unsigned* __restrict__ qcnt,
                   unsigned long long* __restrict__ keysg) {
    if (*qcnt <= CAPQ) return;
    const int t = threadIdx.x;
    const int m0 = blockIdx.x * 64;
#pragma unroll 1
    for (int tok = 0; tok < 64; ++tok) {
        const int token = m0 + tok;
        const float sxv = sxg[token];
        const float* xrow = inp + (size_t)token * D;
        for (int code = t; code < K; code += 256) {
            const float dot = exact_dot512(xrow, cb + (size_t)code * D);
            const float tmp = sxv - 2.0f * dot;
            const float v   = tmp + sc[code];
            const unsigned long long key =
                ((unsigned long long)__float_as_uint(v) << 32) | (unsigned)code;
            atomicMin(&keysg[token], key);
        }
    }
}

// ---------------- gather: bit-exact codebook row copy (UNCHANGED) ----------------------
__global__ __launch_bounds__(256)
void gather_kernel(const float* __restrict__ cb,
                   const unsigned long long* __restrict__ keysg,
                   float* __restrict__ out) {
    const int m0 = blockIdx.x * 64;
    __shared__ int bidx[64];
    if (threadIdx.x < 64) bidx[threadIdx.x] = (int)(keysg[m0 + threadIdx.x] & 0xFFFFFFFFull);
    __syncthreads();
    for (int q = threadIdx.x; q < 64 * (D / 4); q += 256) {
        const int r = q >> 7;
        const int c = (q & 127) * 4;
        *(float4*)(out + (size_t)(m0 + r) * D + c) = *(const float4*)(cb + (size_t)bidx[r] * D + c);
    }
}

// ================= LEGACY (round-1 passing kernel, fallback) ==========
__global__ __launch_bounds__(256)
void vq_kernel(const float* __restrict__ inp, const float* __restrict__ cb,
               const float* __restrict__ sc, float* __restrict__ out) {
    __shared__ __align__(16) float As[BD_LEG][BM + PAD];
    __shared__ __align__(16) float Bs[BD_LEG][BN + PAD];
    __shared__ float sxl[BM];
    __shared__ float scs[BN];
    __shared__ int   bidx[BM];

    const int t  = threadIdx.x;
    const int m0 = blockIdx.x * BM;
    const int tm = t >> 4;
    const int tn = t & 15;
    const float FINF = __builtin_huge_valf();

    {
        const int r = t >> 2, p = t & 3;
        const float* row = inp + (size_t)(m0 + r) * D + p * 128;
        float s = 0.0f;
#pragma unroll
        for (int i = 0; i < 32; ++i) {
            float4 v = *(const float4*)(row + i * 4);
            s = fmaf(v.x, v.x, s); s = fmaf(v.y, v.y, s);
            s = fmaf(v.z, v.z, s); s = fmaf(v.w, v.w, s);
        }
        s += __shfl_xor(s, 1, 64);
        s += __shfl_xor(s, 2, 64);
        if (p == 0) sxl[r] = s;
    }
    __syncthreads();

    float sxm[4];
#pragma unroll
    for (int i = 0; i < 4; ++i) sxm[i] = sxl[tm * 4 + i];

    float runv[4] = {FINF, FINF, FINF, FINF};
    int   runi[4] = {0, 0, 0, 0};
    const int dq = (t & 7) << 2;
    const int mr = t >> 3;

#pragma unroll 1
    for (int kb = 0; kb < K; kb += BN) {
        __syncthreads();
        if (t < BN) scs[t] = sc[kb + t];

        float accl[4][4];
#pragma unroll
        for (int i = 0; i < 4; ++i)
#pragma unroll
            for (int j = 0; j < 4; ++j) accl[i][j] = 0.0f;

#pragma unroll 1
        for (int db = 0; db < D; db += BD_LEG) {
            const float* ap = inp + (size_t)(m0 + mr) * D + db + dq;
            const float* bp = cb  + (size_t)(kb + mr) * D + db + dq;
            float4 av0 = *(const float4*)ap;
            float4 av1 = *(const float4*)(ap + (size_t)32 * D);
            float4 bv0 = *(const float4*)bp;
            float4 bv1 = *(const float4*)(bp + (size_t)32 * D);
            __syncthreads();
            As[dq + 0][mr] = av0.x; As[dq + 1][mr] = av0.y;
            As[dq + 2][mr] = av0.z; As[dq + 3][mr] = av0.w;
            As[dq + 0][mr + 32] = av1.x; As[dq + 1][mr + 32] = av1.y;
            As[dq + 2][mr + 32] = av1.z; As[dq + 3][mr + 32] = av1.w;
            Bs[dq + 0][mr] = bv0.x; Bs[dq + 1][mr] = bv0.y;
            Bs[dq + 2][mr] = bv0.z; Bs[dq + 3][mr] = bv0.w;
            Bs[dq + 0][mr + 32] = bv1.x; Bs[dq + 1][mr + 32] = bv1.y;
            Bs[dq + 2][mr + 32] = bv1.z; Bs[dq + 3][mr + 32] = bv1.w;
            __syncthreads();
#pragma unroll
            for (int d = 0; d < BD_LEG; ++d) {
                const float4 a = *(const float4*)(&As[d][tm * 4]);
                const float4 b = *(const float4*)(&Bs[d][tn * 4]);
                float af[4] = {a.x, a.y, a.z, a.w};
                float bf[4] = {b.x, b.y, b.z, b.w};
#pragma unroll
                for (int i = 0; i < 4; ++i)
#pragma unroll
                    for (int j = 0; j < 4; ++j)
                        accl[i][j] = fmaf(af[i], bf[j], accl[i][j]);
            }
        }
#pragma unroll
        for (int i = 0; i < 4; ++i) {
            float bv = FINF;
            int   bi = 0x7fffffff;
#pragma unroll
            for (int j = 0; j < 4; ++j) {
                const float p = accl[i][j];
                const float tmp = sxm[i] - 2.0f * p;
                const float v   = tmp + scs[tn * 4 + j];
                const int  idx  = kb + tn * 4 + j;
                if (v < bv) { bv = v; bi = idx; }
            }
#pragma unroll
            for (int off = 1; off < 16; off <<= 1) {
                const float ov = __shfl_xor(bv, off, 64);
                const int   oi = __shfl_xor(bi, off, 64);
                if (ov < bv || (ov == bv && oi < bi)) { bv = ov; bi = oi; }
            }
            if (bv < runv[i]) { runv[i] = bv; runi[i] = bi; }
        }
    }
    if (tn == 0) {
#pragma unroll
        for (int i = 0; i < 4; ++i) bidx[tm * 4 + i] = runi[i];
    }
    __syncthreads();
#pragma unroll 1
    for (int q = t; q < BM * (D / 4); q += 256) {
        const int r = q >> 7;
        const int c = (q & 127) * 4;
        const float4 v = *(const float4*)(cb + (size_t)bidx[r] * D + c);
        *(float4*)(out + (size_t)(m0 + r) * D + c) = v;
    }
}

extern "C" void kernel_launch(void* const* d_in, const int* in_sizes, int n_in,
                              void* d_out, int out_size, void* d_ws, size_t ws_size,
                              hipStream_t stream) {
    const float* inp = (const float*)d_in[0];
    const float* cb  = (const float*)d_in[1];
    float* out = (float*)d_out;
    float* sc  = (float*)d_ws;
    const int tokens = in_sizes[0] / D;     // 32768

    const bool fast = (ws_size >= WS_NEED) && (tokens % 256 == 0) &&
                      (in_sizes[1] == K * D) &&
                      ((size_t)out_size * 4 >= (size_t)tokens * D * 2 + (size_t)tokens * 32 * 32);

    if (fast) {
        float* sxg = (float*)((char*)d_ws + SX_OFF);
        unsigned long long* keysg = (unsigned long long*)((char*)d_ws + KEYS_OFF);
        unsigned* qcnt = (unsigned*)((char*)d_ws + QCNT_OFF);
        unsigned short* cbp = (unsigned short*)((char*)d_ws + CBP_OFF);
        unsigned short* ap  = (unsigned short*)d_out;                       // 33.5 MB scratch
        char* records = (char*)d_out + (size_t)tokens * D * 2;              // 33.5 MB scratch
        unsigned* queue = (unsigned*)d_out;                                 // overlays ap (dead after score)

        hipMemsetAsync(qcnt, 0, sizeof(unsigned), stream);
        sc_kernel<<<K / 4, 256, 0, stream>>>(cb, sc);
        sx_kernel<<<tokens / 64, 256, 0, stream>>>(inp, sxg);
        cvt_perm<<<(K * D / 8) / 256, 256, 0, stream>>>(cb, cbp);
        cvt_perm<<<(tokens * D / 8) / 256, 256, 0, stream>>>(inp, ap);
        score_kernel<<<(tokens / 128) * 32, 256, 0, stream>>>(ap, cbp, sc, records);
        compact_kernel<<<tokens / 256, 256, 0, stream>>>(records, keysg, qcnt, queue);
        exec_kernel<<<2048, 256, 0, stream>>>(inp, cb, sc, sxg, qcnt, queue, keysg);
        safety_kernel<<<tokens / 64, 256, 0, stream>>>(inp, cb, sc, sxg, qcnt, keysg);
        gather_kernel<<<tokens / 64, 256, 0, stream>>>(cb, keysg, out);
    } else {
        sc_kernel<<<K / 4, 256, 0, stream>>>(cb, sc);
        vq_kernel<<<tokens / BM, 256, 0, stream>>>(inp, cb, sc, out);
    }
}